// Round 14
// baseline (929.824 us; speedup 1.0000x reference)
//
#include <hip/hip_runtime.h>
#include <hip/hip_bf16.h>

#define B_ROWS   1024
#define N_FEAT   128
#define D_MAIN   256
#define D_INT    512
#define N_CAND   100000
#define CTX      96
#define N_CLS    10
#define PCHN     8192    // pilot chunk size
#define N2       91808   // remaining candidates (fused filter path)
#define RKEEP    128     // refine set size
#define SCAP     6144    // survivor cap per row
#define SVSTRIDE 16      // svcnt padded to one counter per 64B line

typedef __attribute__((ext_vector_type(8))) short bf16x8;
typedef __attribute__((ext_vector_type(4))) float f32x4;
typedef unsigned long long u64;

// ---------- helpers ----------
__device__ __forceinline__ float wsum(float v) {
    #pragma unroll
    for (int o = 32; o > 0; o >>= 1) v += __shfl_down(v, o);
    return v;
}
__device__ __forceinline__ float wmax(float v) {
    #pragma unroll
    for (int o = 32; o > 0; o >>= 1) v = fmaxf(v, __shfl_down(v, o));
    return v;
}
__device__ __forceinline__ float blockSum256(float v, float* red) {
    int t = threadIdx.x;
    float s = wsum(v);
    if ((t & 63) == 0) red[t >> 6] = s;
    __syncthreads();
    s = red[0] + red[1] + red[2] + red[3];
    __syncthreads();
    return s;
}
__device__ __forceinline__ float b2f(unsigned short u) {
    return __uint_as_float(((unsigned)u) << 16);
}
__device__ __forceinline__ unsigned short f2b(float f) {
    unsigned x = __float_as_uint(f);
    return (unsigned short)((x + 0x7fff + ((x >> 16) & 1)) >> 16);
}
__device__ __forceinline__ unsigned fkey(float f) {
    unsigned u = __float_as_uint(f);
    return u ^ ((((int)u >> 31)) | 0x80000000u);
}
__device__ __forceinline__ float finv(unsigned k) {
    unsigned u = (k & 0x80000000u) ? (k ^ 0x80000000u) : ~k;
    return __uint_as_float(u);
}
#define SPLIT1(x, hv, lv) { unsigned short _h = f2b(x); hv = (short)_h; lv = (short)f2b((x) - b2f(_h)); }

// ---------- K1: batch encode (also emits bf16 copy of k) ----------
__global__ __launch_bounds__(256) void encode_batch(
    const float* __restrict__ xn, const float* __restrict__ Wl, const float* __restrict__ bl,
    const float* __restrict__ Wk, const float* __restrict__ bk,
    float* __restrict__ xout, float* __restrict__ kout, float* __restrict__ knorm,
    unsigned short* __restrict__ kbf)
{
    int b = blockIdx.x, t = threadIdx.x;
    __shared__ float si[128], sx[256], red[4];
    if (t < 128) si[t] = xn[b * N_FEAT + t];
    __syncthreads();
    float a = bl[t];
    for (int i = 0; i < 128; ++i) a += si[i] * Wl[i * D_MAIN + t];
    xout[b * D_MAIN + t] = a;
    sx[t] = a;
    __syncthreads();
    float a2 = bk[t];
    for (int i = 0; i < 256; ++i) a2 += sx[i] * Wk[i * D_MAIN + t];
    kout[b * D_MAIN + t] = a2;
    kbf[b * D_MAIN + t] = f2b(a2);
    float s = blockSum256(a2 * a2, red);
    if (t == 0) knorm[b] = s;
}

// ---------- fused encoder weights: Wf = Wl@Wk (fp32), bf = bl@Wk + bk ----------
__global__ __launch_bounds__(256) void fuse_weights(
    const float* __restrict__ Wl, const float* __restrict__ Wk,
    const float* __restrict__ bl, const float* __restrict__ bk,
    float* __restrict__ Wf, float* __restrict__ bf)
{
    int i = blockIdx.x, t = threadIdx.x;
    __shared__ float row[256];
    if (i < 128) {
        row[t] = Wl[i * D_MAIN + t];
        __syncthreads();
        float a = 0.f;
        for (int k = 0; k < 256; ++k) a += row[k] * Wk[k * D_MAIN + t];
        Wf[i * D_MAIN + t] = a;
    } else {
        row[t] = bl[t];
        __syncthreads();
        float a = bk[t];
        for (int k = 0; k < 256; ++k) a += row[k] * Wk[k * D_MAIN + t];
        bf[t] = a;
    }
}

// ---------- split-bf16 fp32-accurate GEMM, 128x64 tile, acc[4][2] ----------
template<bool WRITE_BF16>
__global__ __launch_bounds__(256) void gemm_split3(
    const float* __restrict__ A,
    const unsigned short* __restrict__ Bh,
    const unsigned short* __restrict__ Bl,
    const float* __restrict__ bias,
    float* __restrict__ Cf,
    unsigned short* __restrict__ Cbf,
    int M, int N, int K)
{
    __shared__ __align__(16) short Ash[4096], Asl[4096];   // 128 x 32
    __shared__ __align__(16) short Bsh[2048], Bsl[2048];   // 64 x 32
    const int t = threadIdx.x;
    const int bm = blockIdx.x * 128, bn = blockIdx.y * 64;
    const int wave = t >> 6, lane = t & 63;
    const int wm = (wave >> 1) * 64, wn = (wave & 1) * 32;
    const int lr = lane & 15, lkg = lane >> 4;
    f32x4 acc[4][2] = {};
    const int row0 = t >> 2, kg0 = t & 3;     // row0 in 0..63
    const int row1 = row0 + 64;
    const int p0 = ((kg0 + (row0 >> 2)) & 3) ^ (row0 & 3);
    const int p1 = ((kg0 + (row1 >> 2)) & 3) ^ (row1 & 3);
    const int gm0 = bm + row0, gm1 = bm + row1;
    const int nB = bn + row0;

    float4 u00, u01, u10, u11;
    bf16x8 bh0, bl0;
    auto prefetch = [&](int kq) {
        float4 z4 = make_float4(0.f, 0.f, 0.f, 0.f); bf16x8 z = {};
        u00 = z4; u01 = z4; u10 = z4; u11 = z4;
        bh0 = z; bl0 = z;
        if (gm0 < M) {
            const float* ap = A + (size_t)gm0 * K + kq + kg0 * 8;
            u00 = *(const float4*)ap; u01 = *(const float4*)(ap + 4);
        }
        if (gm1 < M) {
            const float* ap = A + (size_t)gm1 * K + kq + kg0 * 8;
            u10 = *(const float4*)ap; u11 = *(const float4*)(ap + 4);
        }
        if (nB < N) {
            bh0 = *(const bf16x8*)(Bh + (size_t)nB * K + kq + kg0 * 8);
            bl0 = *(const bf16x8*)(Bl + (size_t)nB * K + kq + kg0 * 8);
        }
    };
    prefetch(0);

    for (int k0 = 0; k0 < K; k0 += 32) {
        bf16x8 a0h, a0l, a1h, a1l;
        SPLIT1(u00.x, a0h[0], a0l[0]); SPLIT1(u00.y, a0h[1], a0l[1]);
        SPLIT1(u00.z, a0h[2], a0l[2]); SPLIT1(u00.w, a0h[3], a0l[3]);
        SPLIT1(u01.x, a0h[4], a0l[4]); SPLIT1(u01.y, a0h[5], a0l[5]);
        SPLIT1(u01.z, a0h[6], a0l[6]); SPLIT1(u01.w, a0h[7], a0l[7]);
        SPLIT1(u10.x, a1h[0], a1l[0]); SPLIT1(u10.y, a1h[1], a1l[1]);
        SPLIT1(u10.z, a1h[2], a1l[2]); SPLIT1(u10.w, a1h[3], a1l[3]);
        SPLIT1(u11.x, a1h[4], a1l[4]); SPLIT1(u11.y, a1h[5], a1l[5]);
        SPLIT1(u11.z, a1h[6], a1l[6]); SPLIT1(u11.w, a1h[7], a1l[7]);
        __syncthreads();
        *(bf16x8*)&Ash[(row0 * 4 + p0) * 8] = a0h;
        *(bf16x8*)&Asl[(row0 * 4 + p0) * 8] = a0l;
        *(bf16x8*)&Ash[(row1 * 4 + p1) * 8] = a1h;
        *(bf16x8*)&Asl[(row1 * 4 + p1) * 8] = a1l;
        *(bf16x8*)&Bsh[(row0 * 4 + p0) * 8] = bh0;
        *(bf16x8*)&Bsl[(row0 * 4 + p0) * 8] = bl0;
        if (k0 + 32 < K) prefetch(k0 + 32);
        __syncthreads();
        bf16x8 bfh[2], bfl[2];
        #pragma unroll
        for (int n = 0; n < 2; ++n) {
            int r = wn + n * 16 + lr;
            int p = ((lkg + (r >> 2)) & 3) ^ (r & 3);
            bfh[n] = *(const bf16x8*)&Bsh[(r * 4 + p) * 8];
            bfl[n] = *(const bf16x8*)&Bsl[(r * 4 + p) * 8];
        }
        #pragma unroll
        for (int m = 0; m < 4; ++m) {
            int r = wm + m * 16 + lr;
            int p = ((lkg + (r >> 2)) & 3) ^ (r & 3);
            bf16x8 ah = *(const bf16x8*)&Ash[(r * 4 + p) * 8];
            bf16x8 al = *(const bf16x8*)&Asl[(r * 4 + p) * 8];
            #pragma unroll
            for (int n = 0; n < 2; ++n) {
                acc[m][n] = __builtin_amdgcn_mfma_f32_16x16x32_bf16(al, bfh[n], acc[m][n], 0, 0, 0);
                acc[m][n] = __builtin_amdgcn_mfma_f32_16x16x32_bf16(ah, bfl[n], acc[m][n], 0, 0, 0);
                acc[m][n] = __builtin_amdgcn_mfma_f32_16x16x32_bf16(ah, bfh[n], acc[m][n], 0, 0, 0);
            }
        }
    }
    #pragma unroll
    for (int m = 0; m < 4; ++m) {
        #pragma unroll
        for (int n = 0; n < 2; ++n) {
            f32x4 a = acc[m][n];
            int gcol = bn + wn + n * 16 + lr;
            if (gcol >= N) continue;
            float bv = bias[gcol];
            #pragma unroll
            for (int r = 0; r < 4; ++r) {
                int grow = bm + wm + m * 16 + lkg * 4 + r;
                if (grow >= M) continue;
                float v = a[r] + bv;
                Cf[(size_t)grow * N + gcol] = v;
                if (WRITE_BF16) Cbf[(size_t)grow * N + gcol] = f2b(v);
            }
        }
    }
}

// ---------- T-MLP bf16 GEMM: 128x64 tile, acc[4][2], dbuf LDS (r12-proven) ----------
template<bool RELU, bool OUT_BF16>
__global__ __launch_bounds__(256) void gemm_bf16(
    const unsigned short* __restrict__ A,
    const unsigned short* __restrict__ Bt,
    const float* __restrict__ bias,
    void* __restrict__ C, int M, int N, int K)
{
    __shared__ __align__(16) short As[2][4096];
    __shared__ __align__(16) short Bs[2][2048];
    const int t = threadIdx.x;
    const int bm = blockIdx.x * 128, bn = blockIdx.y * 64;
    const int wave = t >> 6, lane = t & 63;
    const int wm = (wave >> 1) * 64, wn = (wave & 1) * 32;
    const int lr = lane & 15, lkg = lane >> 4;
    f32x4 acc[4][2] = {};
    const int row0 = t >> 2, kg0 = t & 3;
    const int row1 = row0 + 64;
    const int p0 = ((kg0 + (row0 >> 2)) & 3) ^ (row0 & 3);
    const int p1 = ((kg0 + (row1 >> 2)) & 3) ^ (row1 & 3);
    const int gm0 = bm + row0, gm1 = bm + row1;
    const int nB = bn + row0;

    bf16x8 a0, a1, b0;
    auto prefetch = [&](int kq) {
        bf16x8 z = {};
        a0 = z; a1 = z; b0 = z;
        if (gm0 < M) a0 = *(const bf16x8*)(A + (size_t)gm0 * K + kq + kg0 * 8);
        if (gm1 < M) a1 = *(const bf16x8*)(A + (size_t)gm1 * K + kq + kg0 * 8);
        if (nB < N) b0 = *(const bf16x8*)(Bt + (size_t)nB * K + kq + kg0 * 8);
    };
    prefetch(0);
    *(bf16x8*)&As[0][(row0 * 4 + p0) * 8] = a0;
    *(bf16x8*)&As[0][(row1 * 4 + p1) * 8] = a1;
    *(bf16x8*)&Bs[0][(row0 * 4 + p0) * 8] = b0;
    if (32 < K) prefetch(32);
    __syncthreads();

    for (int k0 = 0; k0 < K; k0 += 32) {
        const int cur = (k0 >> 5) & 1;
        if (k0 + 32 < K) {
            const int nxt = cur ^ 1;
            *(bf16x8*)&As[nxt][(row0 * 4 + p0) * 8] = a0;
            *(bf16x8*)&As[nxt][(row1 * 4 + p1) * 8] = a1;
            *(bf16x8*)&Bs[nxt][(row0 * 4 + p0) * 8] = b0;
            if (k0 + 64 < K) prefetch(k0 + 64);
        }
        bf16x8 bfr[2];
        #pragma unroll
        for (int n = 0; n < 2; ++n) {
            int r = wn + n * 16 + lr;
            int p = ((lkg + (r >> 2)) & 3) ^ (r & 3);
            bfr[n] = *(const bf16x8*)&Bs[cur][(r * 4 + p) * 8];
        }
        #pragma unroll
        for (int m = 0; m < 4; ++m) {
            int r = wm + m * 16 + lr;
            int p = ((lkg + (r >> 2)) & 3) ^ (r & 3);
            bf16x8 af = *(const bf16x8*)&As[cur][(r * 4 + p) * 8];
            #pragma unroll
            for (int n = 0; n < 2; ++n)
                acc[m][n] = __builtin_amdgcn_mfma_f32_16x16x32_bf16(
                    af, bfr[n], acc[m][n], 0, 0, 0);
        }
        __syncthreads();
    }
    #pragma unroll
    for (int m = 0; m < 4; ++m) {
        #pragma unroll
        for (int n = 0; n < 2; ++n) {
            f32x4 a = acc[m][n];
            int gcol = bn + wn + n * 16 + lr;
            if (gcol >= N) continue;
            float bv = bias ? bias[gcol] : 0.f;
            #pragma unroll
            for (int r = 0; r < 4; ++r) {
                int grow = bm + wm + m * 16 + lkg * 4 + r;
                if (grow >= M) continue;
                float v = a[r] + bv;
                if (RELU) v = fmaxf(v, 0.f);
                if (OUT_BF16)
                    ((unsigned short*)C)[(size_t)grow * N + gcol] = f2b(v);
                else
                    ((float*)C)[(size_t)grow * N + gcol] = v;
            }
        }
    }
}

// ---------- screen GEMM: barrier-free, LDS-free, per-wave 64x32 tile ----------
// Fragments loaded directly global->VGPR in MFMA layout (16 lanes x 16B = 16
// full 64B lines per instruction), register-double-buffered 2 steps deep.
// Grid: x = 4 wave-groups (1024/256 rows), y = N/32 (N % 32 == 0 guaranteed).
// MODE 1: write scores.  MODE 2: tau-filtered survivor append.
template<int MODE>
__global__ __launch_bounds__(256) void screen_gemm(
    const unsigned short* __restrict__ A,   // k_bf [1024,256]
    const unsigned short* __restrict__ Bt,  // ki_bf span [N,256]
    float* __restrict__ scores,
    int N, int n0,
    const float* __restrict__ knrm,
    const unsigned* __restrict__ tau32, int* __restrict__ svcnt,
    u64* __restrict__ surv)
{
    const int t = threadIdx.x;
    const int wave = t >> 6, lane = t & 63;
    const int lr = lane & 15, lkg = lane >> 4;
    const int bm = (blockIdx.x * 4 + wave) * 64;   // wave-private 64 rows (<1024)
    const int bn = blockIdx.y * 32;                // 32 cols (always < N)
    f32x4 acc[4][2] = {};

    const unsigned short* srcA0 = A + (size_t)(bm + 0 * 16 + lr) * D_MAIN + lkg * 8;
    const unsigned short* srcA1 = A + (size_t)(bm + 1 * 16 + lr) * D_MAIN + lkg * 8;
    const unsigned short* srcA2 = A + (size_t)(bm + 2 * 16 + lr) * D_MAIN + lkg * 8;
    const unsigned short* srcA3 = A + (size_t)(bm + 3 * 16 + lr) * D_MAIN + lkg * 8;
    const unsigned short* srcB0 = Bt + (size_t)(bn + 0 * 16 + lr) * D_MAIN + lkg * 8;
    const unsigned short* srcB1 = Bt + (size_t)(bn + 1 * 16 + lr) * D_MAIN + lkg * 8;

    bf16x8 af[2][4], bfg[2][2];
    #define LOADST(buf, s_) {                                   \
        af[buf][0] = *(const bf16x8*)(srcA0 + (s_) * 32);       \
        af[buf][1] = *(const bf16x8*)(srcA1 + (s_) * 32);       \
        af[buf][2] = *(const bf16x8*)(srcA2 + (s_) * 32);       \
        af[buf][3] = *(const bf16x8*)(srcA3 + (s_) * 32);       \
        bfg[buf][0] = *(const bf16x8*)(srcB0 + (s_) * 32);      \
        bfg[buf][1] = *(const bf16x8*)(srcB1 + (s_) * 32); }
    LOADST(0, 0);
    LOADST(1, 1);
    #pragma unroll
    for (int s = 0; s < 8; ++s) {          // K = 256, 8 steps
        const int cur = s & 1;
        #pragma unroll
        for (int m = 0; m < 4; ++m)
            #pragma unroll
            for (int n = 0; n < 2; ++n)
                acc[m][n] = __builtin_amdgcn_mfma_f32_16x16x32_bf16(
                    af[cur][m], bfg[cur][n], acc[m][n], 0, 0, 0);
        if (s + 2 < 8) LOADST(cur, s + 2);
    }
    #undef LOADST

    float knv[2];
    #pragma unroll
    for (int n = 0; n < 2; ++n) knv[n] = knrm[bn + n * 16 + lr];

    if (MODE == 1) {
        #pragma unroll
        for (int m = 0; m < 4; ++m) {
            #pragma unroll
            for (int n = 0; n < 2; ++n) {
                int gcol = bn + n * 16 + lr;
                #pragma unroll
                for (int r = 0; r < 4; ++r) {
                    int grow = bm + m * 16 + lkg * 4 + r;
                    scores[(size_t)grow * PCHN + gcol] = knv[n] - 2.0f * acc[m][n][r];
                }
            }
        }
    } else {
        unsigned taur[16];
        #pragma unroll
        for (int m = 0; m < 4; ++m)
            #pragma unroll
            for (int r = 0; r < 4; ++r)
                taur[m * 4 + r] = tau32[bm + m * 16 + lkg * 4 + r];
        #pragma unroll
        for (int m = 0; m < 4; ++m) {
            #pragma unroll
            for (int r = 0; r < 4; ++r) {
                int grow = bm + m * 16 + lkg * 4 + r;
                #pragma unroll
                for (int n = 0; n < 2; ++n) {
                    int gcol = bn + n * 16 + lr;
                    unsigned key = fkey(knv[n] - 2.0f * acc[m][n][r]);
                    bool pass = key <= taur[m * 4 + r];
                    u64 bal = __ballot(pass);
                    unsigned g16 = (unsigned)((bal >> (lkg * 16)) & 0xFFFFu);
                    if (g16) {
                        int cntp = __popc(g16);
                        int first = __ffs(g16) - 1;
                        int base = 0;
                        if (lr == first) base = atomicAdd(&svcnt[grow * SVSTRIDE], cntp);
                        base = __shfl(base, lkg * 16 + first);
                        if (pass) {
                            int p = base + __popc(g16 & ((1u << lr) - 1u));
                            if (p < SCAP)
                                surv[(size_t)grow * SCAP + p] =
                                    ((u64)key << 32) | (unsigned)(n0 + gcol);
                        }
                    }
                }
            }
        }
    }
}

// ---------- converts ----------
__global__ __launch_bounds__(256) void cvt_transpose(
    const float* __restrict__ W, unsigned short* __restrict__ Wt, int K, int N)
{
    int idx = blockIdx.x * 256 + threadIdx.x;
    if (idx >= K * N) return;
    int k = idx / N, n = idx % N;
    Wt[(size_t)n * K + k] = f2b(W[idx]);
}
__global__ __launch_bounds__(256) void cvt_split_transpose(
    const float* __restrict__ W, unsigned short* __restrict__ Wh,
    unsigned short* __restrict__ Wl, int K, int N)
{
    int idx = blockIdx.x * 256 + threadIdx.x;
    if (idx >= K * N) return;
    int k = idx / N, n = idx % N;
    float v = W[idx];
    unsigned short h = f2b(v);
    Wh[(size_t)n * K + k] = h;
    Wl[(size_t)n * K + k] = f2b(v - b2f(h));
}

// ---------- row norms ----------
__global__ __launch_bounds__(256) void rownorms(const float* __restrict__ ki,
                                                float* __restrict__ out, int M)
{
    int n = blockIdx.x * 4 + (threadIdx.x >> 6);
    int lane = threadIdx.x & 63;
    if (n >= M) return;
    float4 v = *(const float4*)(ki + (size_t)n * D_MAIN + lane * 4);
    float s = v.x * v.x + v.y * v.y + v.z * v.z + v.w * v.w;
    s = wsum(s);
    if (lane == 0) out[n] = s;
}

// ---------- bitonic sorts ----------
__device__ void bitonic512(u64* s, int t)
{
    for (int k = 2; k <= 512; k <<= 1) {
        for (int j = k >> 1; j > 0; j >>= 1) {
            __syncthreads();
            #pragma unroll
            for (int q = 0; q < 2; ++q) {
                int l = t + q * 256;
                int p = l ^ j;
                if (p > l) {
                    u64 a = s[l], bb = s[p];
                    bool up = ((l & k) == 0);
                    if ((a > bb) == up) { s[l] = bb; s[p] = a; }
                }
            }
        }
    }
    __syncthreads();
}
__device__ void bitonic1024(u64* s, int t)
{
    for (int k = 2; k <= 1024; k <<= 1) {
        for (int j = k >> 1; j > 0; j >>= 1) {
            __syncthreads();
            #pragma unroll
            for (int q = 0; q < 4; ++q) {
                int l = t + q * 256;
                int p = l ^ j;
                if (p > l) {
                    u64 a = s[l], bb = s[p];
                    bool up = ((l & k) == 0);
                    if ((a > bb) == up) { s[l] = bb; s[p] = a; }
                }
            }
        }
    }
    __syncthreads();
}

// ---------- pilot: exact top-128 of pilot scores + tau ----------
__global__ __launch_bounds__(256) void pilot_select(
    const float* __restrict__ scores, u64* __restrict__ pilotbuf,
    unsigned* __restrict__ tau32)
{
    int b = blockIdx.x, t = threadIdx.x;
    int lane = t & 63;
    __shared__ u64 s[1024];
    __shared__ int cnt;
    __shared__ u64 tauf;
    const float* row = scores + (size_t)b * PCHN;
    #pragma unroll
    for (int q = 0; q < 4; ++q) {
        int n = t + q * 256;
        s[n] = ((u64)fkey(row[n]) << 32) | (unsigned)n;
    }
    __syncthreads();
    bitonic1024(s, t);
    if (t == 0) { cnt = 128; tauf = s[127]; }
    #pragma unroll
    for (int q = 0; q < 4; ++q) { int n = t + q * 256; if (n >= 128) s[n] = ~0ULL; }
    __syncthreads();
    for (int base = 1024; base < PCHN; base += 1024) {
        u64 tau = tauf;
        int n = base + t * 4;
        float4 v = *(const float4*)(row + n);
        #pragma unroll
        for (int j = 0; j < 4; ++j) {
            float x = (&v.x)[j];
            u64 e = ((u64)fkey(x) << 32) | (unsigned)(n + j);
            bool pass = e < tau;
            u64 m = __ballot(pass);
            if (m) {
                int bs = 0;
                if (lane == 0) bs = atomicAdd(&cnt, (int)__popcll(m));
                bs = __shfl(bs, 0);
                if (pass) {
                    int p = bs + (int)__popcll(m & ((1ULL << lane) - 1ULL));
                    if (p < 1024) s[p] = e;
                }
            }
        }
        __syncthreads();
        if (cnt > 512) {
            bitonic1024(s, t);
            if (t == 0) { cnt = 128; tauf = s[127]; }
            #pragma unroll
            for (int q = 0; q < 4; ++q) { int n2 = t + q * 256; if (n2 >= 128) s[n2] = ~0ULL; }
        }
        __syncthreads();
    }
    bitonic1024(s, t);
    if (t < 128) pilotbuf[(size_t)b * 128 + t] = s[t];
    if (t == 0) tau32[b] = (unsigned)(s[127] >> 32);
}

// ---------- init survivors from pilot ----------
__global__ __launch_bounds__(128) void init_surv(
    const u64* __restrict__ pilotbuf, u64* __restrict__ surv, int* __restrict__ svcnt)
{
    int b = blockIdx.x, t = threadIdx.x;
    surv[(size_t)b * SCAP + t] = pilotbuf[(size_t)b * 128 + t];
    if (t == 0) svcnt[b * SVSTRIDE] = 128;
}

// ---------- final: exact top-128 of survivor set -> refI ----------
__global__ __launch_bounds__(256) void final_select(
    const u64* __restrict__ surv, const int* __restrict__ svcnt,
    int* __restrict__ refI)
{
    int b = blockIdx.x, t = threadIdx.x;
    int lane = t & 63;
    __shared__ u64 s[1024];
    __shared__ int cnt;
    __shared__ u64 tauf;
    int total = svcnt[b * SVSTRIDE]; if (total > SCAP) total = SCAP;
    const u64* rowp = surv + (size_t)b * SCAP;
    #pragma unroll
    for (int q = 0; q < 4; ++q) {
        int n = t + q * 256;
        s[n] = (n < total) ? rowp[n] : ~0ULL;
    }
    __syncthreads();
    bitonic1024(s, t);
    if (t == 0) { cnt = 128; tauf = s[127]; }
    #pragma unroll
    for (int q = 0; q < 4; ++q) { int n = t + q * 256; if (n >= 128) s[n] = ~0ULL; }
    __syncthreads();
    for (int base = 1024; base < total; base += 1024) {
        u64 tau = tauf;
        int n = base + t * 4;
        #pragma unroll
        for (int j = 0; j < 4; ++j) {
            u64 e = (n + j < total) ? rowp[n + j] : ~0ULL;
            bool pass = e < tau;
            u64 m = __ballot(pass);
            if (m) {
                int bs = 0;
                if (lane == 0) bs = atomicAdd(&cnt, (int)__popcll(m));
                bs = __shfl(bs, 0);
                if (pass) {
                    int p = bs + (int)__popcll(m & ((1ULL << lane) - 1ULL));
                    if (p < 1024) s[p] = e;
                }
            }
        }
        __syncthreads();
        if (cnt > 512) {
            bitonic1024(s, t);
            if (t == 0) { cnt = 128; tauf = s[127]; }
            #pragma unroll
            for (int q = 0; q < 4; ++q) { int n2 = t + q * 256; if (n2 >= 128) s[n2] = ~0ULL; }
        }
        __syncthreads();
    }
    bitonic1024(s, t);
    if (t < RKEEP) refI[b * RKEEP + t] = (int)(unsigned)(s[t] & 0xffffffffULL);
}

// ---------- exact fp32 refine of RKEEP survivors -> top-96 + S ----------
__global__ __launch_bounds__(256) void refine(
    const float* __restrict__ kmat, const float* __restrict__ kiall,
    const float* __restrict__ knorm, const float* __restrict__ kinorm,
    const int* __restrict__ refI, int* __restrict__ Ifin, float* __restrict__ Sbuf)
{
    int b = blockIdx.x, t = threadIdx.x;
    int w = t >> 6, lane = t & 63;
    __shared__ float kk[256];
    __shared__ u64 s[512];
    kk[t] = kmat[b * D_MAIN + t];
    s[t] = ~0ULL; s[t + 256] = ~0ULL;
    __syncthreads();
    float kn = knorm[b];
    for (int sv = w; sv < RKEEP; sv += 4) {
        int n = refI[b * RKEEP + sv];
        float4 a = *(const float4*)&kk[lane * 4];
        float4 bb = ((const float4*)(kiall + (size_t)n * D_MAIN))[lane];
        float d = a.x * bb.x + a.y * bb.y + a.z * bb.z + a.w * bb.w;
        d = wsum(d);
        if (lane == 0) {
            float d2 = kn + kinorm[n] - 2.f * d;
            s[sv] = ((u64)fkey(d2) << 32) | (unsigned)n;
        }
    }
    __syncthreads();
    bitonic512(s, t);
    if (t < CTX) {
        u64 e = s[t];
        Ifin[b * CTX + t] = (int)(unsigned)(e & 0xffffffffULL);
        Sbuf[b * CTX + t] = finv((unsigned)(e >> 32));
    }
}

// ---------- gather diff (bf16) ----------
__global__ __launch_bounds__(64) void gather_diff_bf(
    const float* __restrict__ kmat, const float* __restrict__ kiall,
    const int* __restrict__ I, unsigned short* __restrict__ diffb)
{
    int bc = blockIdx.x;
    int b = bc / CTX;
    int t = threadIdx.x;
    int idx = I[bc];
    float4 kv = ((const float4*)(kmat + (size_t)b * D_MAIN))[t];
    float4 iv = ((const float4*)(kiall + (size_t)idx * D_MAIN))[t];
    ushort4 u;
    u.x = f2b(kv.x - iv.x); u.y = f2b(kv.y - iv.y);
    u.z = f2b(kv.z - iv.z); u.w = f2b(kv.w - iv.w);
    ((ushort4*)(diffb + (size_t)bc * D_MAIN))[t] = u;
}

// ---------- softmax over 96 ----------
__global__ __launch_bounds__(128) void softmax96(const float* __restrict__ S,
                                                 float* __restrict__ w)
{
    int b = blockIdx.x, t = threadIdx.x;
    __shared__ float rm[2], rs[2];
    float v = (t < CTX) ? S[b * CTX + t] : -__builtin_inff();
    float m = wmax(v);
    if ((t & 63) == 0) rm[t >> 6] = m;
    __syncthreads();
    m = fmaxf(rm[0], rm[1]);
    float e = (t < CTX) ? expf(v - m) : 0.f;
    float ss = wsum(e);
    if ((t & 63) == 0) rs[t >> 6] = ss;
    __syncthreads();
    float Z = rs[0] + rs[1];
    if (t < CTX) w[b * CTX + t] = e / Z;
}

// ---------- aggregation ----------
__global__ __launch_bounds__(256) void aggregate(
    const float* __restrict__ w, const int* __restrict__ I,
    const int* __restrict__ cand_y, const float* __restrict__ Yemb,
    const float* __restrict__ mlp, const float* __restrict__ x,
    float* __restrict__ x2)
{
    int b = blockIdx.x, t = threadIdx.x;
    __shared__ float ws[CTX];
    __shared__ int lab[CTX];
    if (t < CTX) {
        ws[t] = w[b * CTX + t];
        lab[t] = cand_y[I[b * CTX + t]];
    }
    __syncthreads();
    float acc = 0.f;
    for (int c = 0; c < CTX; ++c) {
        acc += ws[c] * (Yemb[lab[c] * D_MAIN + t] + mlp[((size_t)b * CTX + c) * D_MAIN + t]);
    }
    x2[b * D_MAIN + t] = x[b * D_MAIN + t] + acc;
}

// ---------- predictor block + head ----------
__global__ __launch_bounds__(256) void predictor_head(
    const float* __restrict__ x2,
    const float* __restrict__ lns, const float* __restrict__ lnb,
    const float* __restrict__ W1, const float* __restrict__ b1,
    const float* __restrict__ W2, const float* __restrict__ b2,
    const float* __restrict__ plns, const float* __restrict__ plnb,
    const float* __restrict__ PW, const float* __restrict__ Pb,
    float* __restrict__ out)
{
    int b = blockIdx.x, t = threadIdx.x;
    __shared__ float ln1[256], hdn[512], red[4];
    float xv = x2[b * D_MAIN + t];
    float s1 = blockSum256(xv, red);
    float s2 = blockSum256(xv * xv, red);
    float mean = s1 * (1.f / 256.f);
    float var = s2 * (1.f / 256.f) - mean * mean;
    float rstd = rsqrtf(var + 1e-5f);
    ln1[t] = (xv - mean) * rstd * lns[t] + lnb[t];
    __syncthreads();
    #pragma unroll
    for (int rep = 0; rep < 2; ++rep) {
        int j = t + rep * 256;
        float a = b1[j];
        for (int i = 0; i < 256; ++i) a += ln1[i] * W1[i * D_INT + j];
        hdn[j] = fmaxf(a, 0.f);
    }
    __syncthreads();
    float a3 = b2[t];
    for (int i = 0; i < 512; ++i) a3 += hdn[i] * W2[i * D_MAIN + t];
    float x3 = xv + a3;
    float s3 = blockSum256(x3, red);
    float s4 = blockSum256(x3 * x3, red);
    float m2 = s3 * (1.f / 256.f);
    float v2 = s4 * (1.f / 256.f) - m2 * m2;
    float r2 = rsqrtf(v2 + 1e-5f);
    float rv = fmaxf((x3 - m2) * r2 * plns[t] + plnb[t], 0.f);
    __syncthreads();
    ln1[t] = rv;
    __syncthreads();
    if (t < N_CLS) {
        float a = Pb[t];
        for (int i = 0; i < 256; ++i) a += ln1[i] * PW[i * N_CLS + t];
        out[b * N_CLS + t] = a;
    }
}

// ---------- host-side launch ----------
extern "C" void kernel_launch(void* const* d_in, const int* in_sizes, int n_in,
                              void* d_out, int out_size, void* d_ws, size_t ws_size,
                              hipStream_t stream)
{
    (void)in_sizes; (void)n_in; (void)out_size; (void)ws_size;
    const float* x_num   = (const float*)d_in[0];
    const float* cand    = (const float*)d_in[1];
    const int*   cand_y  = (const int*)d_in[2];
    const float* W_lin   = (const float*)d_in[4];
    const float* b_lin   = (const float*)d_in[5];
    const float* W_K     = (const float*)d_in[6];
    const float* b_K     = (const float*)d_in[7];
    const float* Y_emb   = (const float*)d_in[8];
    const float* T_W1    = (const float*)d_in[9];
    const float* T_b1    = (const float*)d_in[10];
    const float* T_W2    = (const float*)d_in[11];
    const float* bp_ln_s = (const float*)d_in[12];
    const float* bp_ln_b = (const float*)d_in[13];
    const float* bp_W1   = (const float*)d_in[14];
    const float* bp_b1   = (const float*)d_in[15];
    const float* bp_W2   = (const float*)d_in[16];
    const float* bp_b2   = (const float*)d_in[17];
    const float* P_ln_s  = (const float*)d_in[18];
    const float* P_ln_b  = (const float*)d_in[19];
    const float* P_W     = (const float*)d_in[20];
    const float* P_b     = (const float*)d_in[21];
    float* outp = (float*)d_out;

    char* ws = (char*)d_ws;
    float* kiall  = (float*)(ws + 0);
    unsigned short* hidden = (unsigned short*)(ws + 0);
    unsigned short* ki_bf = (unsigned short*)(ws + 102400000);
    unsigned short* diffb = (unsigned short*)(ws + 102400000);
    float* mlpbuf = (float*)(ws + 102400000);
    float* scores = (float*)(ws + 153600000);
    u64*   surv   = (u64*)(ws + 153600000);
    const size_t T = 204800000;
    float* xbuf   = (float*)(ws + T + 0);
    float* kbuf   = (float*)(ws + T + 1048576);
    float* x2buf  = (float*)(ws + T + 2097152);
    float* knorm  = (float*)(ws + T + 3145728);
    float* kinorm = (float*)(ws + T + 3149824);
    unsigned short* k_bf = (unsigned short*)(ws + T + 3551232);
    float* Wf     = (float*)(ws + T + 4075520);            // 128x256 f32
    unsigned short* WfH = (unsigned short*)(ws + T + 4206592);  // 256x128 bf16
    unsigned short* WfL = (unsigned short*)(ws + T + 4272128);
    float* bfused = (float*)(ws + T + 4337664);            // 256 f32
    unsigned short* W1t  = (unsigned short*)(ws + T + 4468736);
    unsigned short* W2t  = (unsigned short*)(ws + T + 4730880);
    float* Sbuf   = (float*)(ws + T + 4993024);
    float* wbuf   = (float*)(ws + T + 5386240);
    int*   refI   = (int*)(ws + T + 5779456);
    int*   Ifin   = (int*)(ws + T + 6303744);
    u64*   pilotbuf = (u64*)(ws + T + 6696960);
    unsigned* tau32 = (unsigned*)(ws + T + 7745536);
    int*   svcnt  = (int*)(ws + T + 7749632);

    // 1. batch encode (exact fp32, fused bf16 emit)
    encode_batch<<<B_ROWS, 256, 0, stream>>>(x_num, W_lin, b_lin, W_K, b_K,
                                             xbuf, kbuf, knorm, k_bf);
    // 2. fused encoder weights (fp32): Wf = Wl@Wk, bf = bl@Wk + bk; split to bf16
    fuse_weights<<<129, 256, 0, stream>>>(W_lin, W_K, b_lin, b_K, Wf, bfused);
    cvt_split_transpose<<<128, 256, 0, stream>>>(Wf, WfH, WfL, N_FEAT, D_MAIN);
    cvt_transpose<<<512, 256, 0, stream>>>(T_W1, W1t, D_MAIN, D_INT);
    cvt_transpose<<<512, 256, 0, stream>>>(T_W2, W2t, D_INT, D_MAIN);
    // 3. candidate keys via ONE fused split-bf16 GEMM (fp32-accurate), K=128
    gemm_split3<true><<<dim3(782, 4), 256, 0, stream>>>(
        cand, WfH, WfL, bfused, kiall, ki_bf, N_CAND, D_MAIN, N_FEAT);
    // 4. candidate norms
    rownorms<<<25000, 256, 0, stream>>>(kiall, kinorm, N_CAND);
    // 5. pilot: screen first PCHN candidates, exact top-128 + tau
    screen_gemm<1><<<dim3(4, PCHN / 32), 256, 0, stream>>>(
        k_bf, ki_bf, scores, PCHN, 0, kinorm, nullptr, nullptr, nullptr);
    pilot_select<<<B_ROWS, 256, 0, stream>>>(scores, pilotbuf, tau32);
    init_surv<<<B_ROWS, 128, 0, stream>>>(pilotbuf, surv, svcnt);
    // 6. fused screen+filter over remaining candidates (barrier-free)
    screen_gemm<2><<<dim3(4, N2 / 32), 256, 0, stream>>>(
        k_bf, ki_bf + (size_t)PCHN * D_MAIN, nullptr, N2, PCHN,
        kinorm + PCHN, tau32, svcnt, surv);
    // 7. final exact top-128 of survivors -> refI
    final_select<<<B_ROWS, 256, 0, stream>>>(surv, svcnt, refI);
    // 8. exact fp32 refine -> top-96 + S
    refine<<<B_ROWS, 256, 0, stream>>>(kbuf, kiall, knorm, kinorm, refI, Ifin, Sbuf);
    // 9. softmax weights
    softmax96<<<B_ROWS, 128, 0, stream>>>(Sbuf, wbuf);
    // 10. gather diff (bf16)
    gather_diff_bf<<<B_ROWS * CTX, 64, 0, stream>>>(kbuf, kiall, Ifin, diffb);
    // 11. T-MLP on MFMA (128x64 tiles, dbuf)
    gemm_bf16<true, true><<<dim3(768, 8), 256, 0, stream>>>(
        diffb, W1t, T_b1, hidden, B_ROWS * CTX, D_INT, D_MAIN);
    gemm_bf16<false, false><<<dim3(768, 4), 256, 0, stream>>>(
        hidden, W2t, nullptr, mlpbuf, B_ROWS * CTX, D_MAIN, D_INT);
    // 12. aggregate
    aggregate<<<B_ROWS, 256, 0, stream>>>(wbuf, Ifin, cand_y, Y_emb, mlpbuf,
                                          xbuf, x2buf);
    // 13. predictor + head
    predictor_head<<<B_ROWS, 256, 0, stream>>>(x2buf, bp_ln_s, bp_ln_b,
                                               bp_W1, bp_b1, bp_W2, bp_b2,
                                               P_ln_s, P_ln_b, P_W, P_b, outp);
}

// Round 15
// 888.357 us; speedup vs baseline: 1.0467x; 1.0467x over previous
//
#include <hip/hip_runtime.h>
#include <hip/hip_bf16.h>

#define B_ROWS   1024
#define N_FEAT   128
#define D_MAIN   256
#define D_INT    512
#define N_CAND   100000
#define CTX      96
#define N_CLS    10
#define PCHN     4096    // pilot chunk size
#define N2       95904   // remaining candidates (fused filter path)
#define RKEEP    128     // refine set size
#define SCAP     6144    // survivor cap per row
#define SVSTRIDE 16      // svcnt padded to one counter per 64B line

typedef __attribute__((ext_vector_type(8))) short bf16x8;
typedef __attribute__((ext_vector_type(4))) float f32x4;
typedef unsigned long long u64;

// ---------- helpers ----------
__device__ __forceinline__ float wsum(float v) {
    #pragma unroll
    for (int o = 32; o > 0; o >>= 1) v += __shfl_down(v, o);
    return v;
}
__device__ __forceinline__ float wmax(float v) {
    #pragma unroll
    for (int o = 32; o > 0; o >>= 1) v = fmaxf(v, __shfl_down(v, o));
    return v;
}
__device__ __forceinline__ float blockSum256(float v, float* red) {
    int t = threadIdx.x;
    float s = wsum(v);
    if ((t & 63) == 0) red[t >> 6] = s;
    __syncthreads();
    s = red[0] + red[1] + red[2] + red[3];
    __syncthreads();
    return s;
}
__device__ __forceinline__ float b2f(unsigned short u) {
    return __uint_as_float(((unsigned)u) << 16);
}
__device__ __forceinline__ unsigned short f2b(float f) {
    unsigned x = __float_as_uint(f);
    return (unsigned short)((x + 0x7fff + ((x >> 16) & 1)) >> 16);
}
__device__ __forceinline__ unsigned fkey(float f) {
    unsigned u = __float_as_uint(f);
    return u ^ ((((int)u >> 31)) | 0x80000000u);
}
__device__ __forceinline__ float finv(unsigned k) {
    unsigned u = (k & 0x80000000u) ? (k ^ 0x80000000u) : ~k;
    return __uint_as_float(u);
}
#define SPLIT1(x, hv, lv) { unsigned short _h = f2b(x); hv = (short)_h; lv = (short)f2b((x) - b2f(_h)); }

// ---------- K1: batch encode (also emits bf16 copy of k) ----------
__global__ __launch_bounds__(256) void encode_batch(
    const float* __restrict__ xn, const float* __restrict__ Wl, const float* __restrict__ bl,
    const float* __restrict__ Wk, const float* __restrict__ bk,
    float* __restrict__ xout, float* __restrict__ kout, float* __restrict__ knorm,
    unsigned short* __restrict__ kbf)
{
    int b = blockIdx.x, t = threadIdx.x;
    __shared__ float si[128], sx[256], red[4];
    if (t < 128) si[t] = xn[b * N_FEAT + t];
    __syncthreads();
    float a = bl[t];
    for (int i = 0; i < 128; ++i) a += si[i] * Wl[i * D_MAIN + t];
    xout[b * D_MAIN + t] = a;
    sx[t] = a;
    __syncthreads();
    float a2 = bk[t];
    for (int i = 0; i < 256; ++i) a2 += sx[i] * Wk[i * D_MAIN + t];
    kout[b * D_MAIN + t] = a2;
    kbf[b * D_MAIN + t] = f2b(a2);
    float s = blockSum256(a2 * a2, red);
    if (t == 0) knorm[b] = s;
}

// ---------- fused encoder weights: Wf = Wl@Wk (fp32), bf = bl@Wk + bk ----------
__global__ __launch_bounds__(256) void fuse_weights(
    const float* __restrict__ Wl, const float* __restrict__ Wk,
    const float* __restrict__ bl, const float* __restrict__ bk,
    float* __restrict__ Wf, float* __restrict__ bf)
{
    int i = blockIdx.x, t = threadIdx.x;
    __shared__ float row[256];
    if (i < 128) {
        row[t] = Wl[i * D_MAIN + t];
        __syncthreads();
        float a = 0.f;
        for (int k = 0; k < 256; ++k) a += row[k] * Wk[k * D_MAIN + t];
        Wf[i * D_MAIN + t] = a;
    } else {
        row[t] = bl[t];
        __syncthreads();
        float a = bk[t];
        for (int k = 0; k < 256; ++k) a += row[k] * Wk[k * D_MAIN + t];
        bf[t] = a;
    }
}

// ---------- split-bf16 fp32-accurate GEMM, 128x64 tile, acc[4][2] ----------
template<bool WRITE_BF16>
__global__ __launch_bounds__(256) void gemm_split3(
    const float* __restrict__ A,
    const unsigned short* __restrict__ Bh,
    const unsigned short* __restrict__ Bl,
    const float* __restrict__ bias,
    float* __restrict__ Cf,
    unsigned short* __restrict__ Cbf,
    int M, int N, int K)
{
    __shared__ __align__(16) short Ash[4096], Asl[4096];   // 128 x 32
    __shared__ __align__(16) short Bsh[2048], Bsl[2048];   // 64 x 32
    const int t = threadIdx.x;
    const int bm = blockIdx.x * 128, bn = blockIdx.y * 64;
    const int wave = t >> 6, lane = t & 63;
    const int wm = (wave >> 1) * 64, wn = (wave & 1) * 32;
    const int lr = lane & 15, lkg = lane >> 4;
    f32x4 acc[4][2] = {};
    const int row0 = t >> 2, kg0 = t & 3;     // row0 in 0..63
    const int row1 = row0 + 64;
    const int p0 = ((kg0 + (row0 >> 2)) & 3) ^ (row0 & 3);
    const int p1 = ((kg0 + (row1 >> 2)) & 3) ^ (row1 & 3);
    const int gm0 = bm + row0, gm1 = bm + row1;
    const int nB = bn + row0;

    float4 u00, u01, u10, u11;
    bf16x8 bh0, bl0;
    auto prefetch = [&](int kq) {
        float4 z4 = make_float4(0.f, 0.f, 0.f, 0.f); bf16x8 z = {};
        u00 = z4; u01 = z4; u10 = z4; u11 = z4;
        bh0 = z; bl0 = z;
        if (gm0 < M) {
            const float* ap = A + (size_t)gm0 * K + kq + kg0 * 8;
            u00 = *(const float4*)ap; u01 = *(const float4*)(ap + 4);
        }
        if (gm1 < M) {
            const float* ap = A + (size_t)gm1 * K + kq + kg0 * 8;
            u10 = *(const float4*)ap; u11 = *(const float4*)(ap + 4);
        }
        if (nB < N) {
            bh0 = *(const bf16x8*)(Bh + (size_t)nB * K + kq + kg0 * 8);
            bl0 = *(const bf16x8*)(Bl + (size_t)nB * K + kq + kg0 * 8);
        }
    };
    prefetch(0);

    for (int k0 = 0; k0 < K; k0 += 32) {
        bf16x8 a0h, a0l, a1h, a1l;
        SPLIT1(u00.x, a0h[0], a0l[0]); SPLIT1(u00.y, a0h[1], a0l[1]);
        SPLIT1(u00.z, a0h[2], a0l[2]); SPLIT1(u00.w, a0h[3], a0l[3]);
        SPLIT1(u01.x, a0h[4], a0l[4]); SPLIT1(u01.y, a0h[5], a0l[5]);
        SPLIT1(u01.z, a0h[6], a0l[6]); SPLIT1(u01.w, a0h[7], a0l[7]);
        SPLIT1(u10.x, a1h[0], a1l[0]); SPLIT1(u10.y, a1h[1], a1l[1]);
        SPLIT1(u10.z, a1h[2], a1l[2]); SPLIT1(u10.w, a1h[3], a1l[3]);
        SPLIT1(u11.x, a1h[4], a1l[4]); SPLIT1(u11.y, a1h[5], a1l[5]);
        SPLIT1(u11.z, a1h[6], a1l[6]); SPLIT1(u11.w, a1h[7], a1l[7]);
        __syncthreads();
        *(bf16x8*)&Ash[(row0 * 4 + p0) * 8] = a0h;
        *(bf16x8*)&Asl[(row0 * 4 + p0) * 8] = a0l;
        *(bf16x8*)&Ash[(row1 * 4 + p1) * 8] = a1h;
        *(bf16x8*)&Asl[(row1 * 4 + p1) * 8] = a1l;
        *(bf16x8*)&Bsh[(row0 * 4 + p0) * 8] = bh0;
        *(bf16x8*)&Bsl[(row0 * 4 + p0) * 8] = bl0;
        if (k0 + 32 < K) prefetch(k0 + 32);
        __syncthreads();
        bf16x8 bfh[2], bfl[2];
        #pragma unroll
        for (int n = 0; n < 2; ++n) {
            int r = wn + n * 16 + lr;
            int p = ((lkg + (r >> 2)) & 3) ^ (r & 3);
            bfh[n] = *(const bf16x8*)&Bsh[(r * 4 + p) * 8];
            bfl[n] = *(const bf16x8*)&Bsl[(r * 4 + p) * 8];
        }
        #pragma unroll
        for (int m = 0; m < 4; ++m) {
            int r = wm + m * 16 + lr;
            int p = ((lkg + (r >> 2)) & 3) ^ (r & 3);
            bf16x8 ah = *(const bf16x8*)&Ash[(r * 4 + p) * 8];
            bf16x8 al = *(const bf16x8*)&Asl[(r * 4 + p) * 8];
            #pragma unroll
            for (int n = 0; n < 2; ++n) {
                acc[m][n] = __builtin_amdgcn_mfma_f32_16x16x32_bf16(al, bfh[n], acc[m][n], 0, 0, 0);
                acc[m][n] = __builtin_amdgcn_mfma_f32_16x16x32_bf16(ah, bfl[n], acc[m][n], 0, 0, 0);
                acc[m][n] = __builtin_amdgcn_mfma_f32_16x16x32_bf16(ah, bfh[n], acc[m][n], 0, 0, 0);
            }
        }
    }
    #pragma unroll
    for (int m = 0; m < 4; ++m) {
        #pragma unroll
        for (int n = 0; n < 2; ++n) {
            f32x4 a = acc[m][n];
            int gcol = bn + wn + n * 16 + lr;
            if (gcol >= N) continue;
            float bv = bias[gcol];
            #pragma unroll
            for (int r = 0; r < 4; ++r) {
                int grow = bm + wm + m * 16 + lkg * 4 + r;
                if (grow >= M) continue;
                float v = a[r] + bv;
                Cf[(size_t)grow * N + gcol] = v;
                if (WRITE_BF16) Cbf[(size_t)grow * N + gcol] = f2b(v);
            }
        }
    }
}

// ---------- T-MLP bf16 GEMM: 128x64 tile, acc[4][2], dbuf LDS (1 barrier/K-step) ----------
template<bool RELU, bool OUT_BF16>
__global__ __launch_bounds__(256) void gemm_bf16(
    const unsigned short* __restrict__ A,
    const unsigned short* __restrict__ Bt,
    const float* __restrict__ bias,
    void* __restrict__ C, int M, int N, int K)
{
    __shared__ __align__(16) short As[2][4096];
    __shared__ __align__(16) short Bs[2][2048];
    const int t = threadIdx.x;
    const int bm = blockIdx.x * 128, bn = blockIdx.y * 64;
    const int wave = t >> 6, lane = t & 63;
    const int wm = (wave >> 1) * 64, wn = (wave & 1) * 32;
    const int lr = lane & 15, lkg = lane >> 4;
    f32x4 acc[4][2] = {};
    const int row0 = t >> 2, kg0 = t & 3;
    const int row1 = row0 + 64;
    const int p0 = ((kg0 + (row0 >> 2)) & 3) ^ (row0 & 3);
    const int p1 = ((kg0 + (row1 >> 2)) & 3) ^ (row1 & 3);
    const int gm0 = bm + row0, gm1 = bm + row1;
    const int nB = bn + row0;

    bf16x8 a0, a1, b0;
    auto prefetch = [&](int kq) {
        bf16x8 z = {};
        a0 = z; a1 = z; b0 = z;
        if (gm0 < M) a0 = *(const bf16x8*)(A + (size_t)gm0 * K + kq + kg0 * 8);
        if (gm1 < M) a1 = *(const bf16x8*)(A + (size_t)gm1 * K + kq + kg0 * 8);
        if (nB < N) b0 = *(const bf16x8*)(Bt + (size_t)nB * K + kq + kg0 * 8);
    };
    prefetch(0);
    *(bf16x8*)&As[0][(row0 * 4 + p0) * 8] = a0;
    *(bf16x8*)&As[0][(row1 * 4 + p1) * 8] = a1;
    *(bf16x8*)&Bs[0][(row0 * 4 + p0) * 8] = b0;
    if (32 < K) prefetch(32);
    __syncthreads();

    for (int k0 = 0; k0 < K; k0 += 32) {
        const int cur = (k0 >> 5) & 1;
        if (k0 + 32 < K) {
            const int nxt = cur ^ 1;
            *(bf16x8*)&As[nxt][(row0 * 4 + p0) * 8] = a0;
            *(bf16x8*)&As[nxt][(row1 * 4 + p1) * 8] = a1;
            *(bf16x8*)&Bs[nxt][(row0 * 4 + p0) * 8] = b0;
            if (k0 + 64 < K) prefetch(k0 + 64);
        }
        bf16x8 bfr[2];
        #pragma unroll
        for (int n = 0; n < 2; ++n) {
            int r = wn + n * 16 + lr;
            int p = ((lkg + (r >> 2)) & 3) ^ (r & 3);
            bfr[n] = *(const bf16x8*)&Bs[cur][(r * 4 + p) * 8];
        }
        #pragma unroll
        for (int m = 0; m < 4; ++m) {
            int r = wm + m * 16 + lr;
            int p = ((lkg + (r >> 2)) & 3) ^ (r & 3);
            bf16x8 af = *(const bf16x8*)&As[cur][(r * 4 + p) * 8];
            #pragma unroll
            for (int n = 0; n < 2; ++n)
                acc[m][n] = __builtin_amdgcn_mfma_f32_16x16x32_bf16(
                    af, bfr[n], acc[m][n], 0, 0, 0);
        }
        __syncthreads();
    }
    #pragma unroll
    for (int m = 0; m < 4; ++m) {
        #pragma unroll
        for (int n = 0; n < 2; ++n) {
            f32x4 a = acc[m][n];
            int gcol = bn + wn + n * 16 + lr;
            if (gcol >= N) continue;
            float bv = bias ? bias[gcol] : 0.f;
            #pragma unroll
            for (int r = 0; r < 4; ++r) {
                int grow = bm + wm + m * 16 + lkg * 4 + r;
                if (grow >= M) continue;
                float v = a[r] + bv;
                if (RELU) v = fmaxf(v, 0.f);
                if (OUT_BF16)
                    ((unsigned short*)C)[(size_t)grow * N + gcol] = f2b(v);
                else
                    ((float*)C)[(size_t)grow * N + gcol] = v;
            }
        }
    }
}

// ---------- screen GEMM: 128x64 tile, acc[4][2], dbuf LDS (1 barrier/K-step) ----------
// MODE 1: write scores.  MODE 2: tau-filtered survivor append.
template<int MODE>
__global__ __launch_bounds__(256) void screen_gemm(
    const unsigned short* __restrict__ A,   // k_bf [1024,256]
    const unsigned short* __restrict__ Bt,  // ki_bf span [N,256]
    float* __restrict__ scores,
    int N, int n0,
    const float* __restrict__ knrm,
    const unsigned* __restrict__ tau32, int* __restrict__ svcnt,
    u64* __restrict__ surv)
{
    __shared__ __align__(16) short As[2][4096];
    __shared__ __align__(16) short Bs[2][2048];
    const int t = threadIdx.x;
    const int bm = blockIdx.x * 128, bn = blockIdx.y * 64;
    const int wave = t >> 6, lane = t & 63;
    const int wm = (wave >> 1) * 64, wn = (wave & 1) * 32;
    const int lr = lane & 15, lkg = lane >> 4;
    f32x4 acc[4][2] = {};
    const int row0 = t >> 2, kg0 = t & 3;
    const int row1 = row0 + 64;
    const int p0 = ((kg0 + (row0 >> 2)) & 3) ^ (row0 & 3);
    const int p1 = ((kg0 + (row1 >> 2)) & 3) ^ (row1 & 3);
    const int gm0 = bm + row0, gm1 = bm + row1;   // < 1024 always
    const int nB = bn + row0;

    bf16x8 a0, a1, b0;
    auto prefetch = [&](int kq) {
        bf16x8 z = {};
        b0 = z;
        a0 = *(const bf16x8*)(A + (size_t)gm0 * D_MAIN + kq + kg0 * 8);
        a1 = *(const bf16x8*)(A + (size_t)gm1 * D_MAIN + kq + kg0 * 8);
        if (nB < N) b0 = *(const bf16x8*)(Bt + (size_t)nB * D_MAIN + kq + kg0 * 8);
    };
    prefetch(0);
    *(bf16x8*)&As[0][(row0 * 4 + p0) * 8] = a0;
    *(bf16x8*)&As[0][(row1 * 4 + p1) * 8] = a1;
    *(bf16x8*)&Bs[0][(row0 * 4 + p0) * 8] = b0;
    prefetch(32);
    __syncthreads();

    for (int k0 = 0; k0 < D_MAIN; k0 += 32) {
        const int cur = (k0 >> 5) & 1;
        if (k0 + 32 < D_MAIN) {
            const int nxt = cur ^ 1;
            *(bf16x8*)&As[nxt][(row0 * 4 + p0) * 8] = a0;
            *(bf16x8*)&As[nxt][(row1 * 4 + p1) * 8] = a1;
            *(bf16x8*)&Bs[nxt][(row0 * 4 + p0) * 8] = b0;
            if (k0 + 64 < D_MAIN) prefetch(k0 + 64);
        }
        bf16x8 bfr[2];
        #pragma unroll
        for (int n = 0; n < 2; ++n) {
            int r = wn + n * 16 + lr;
            int p = ((lkg + (r >> 2)) & 3) ^ (r & 3);
            bfr[n] = *(const bf16x8*)&Bs[cur][(r * 4 + p) * 8];
        }
        #pragma unroll
        for (int m = 0; m < 4; ++m) {
            int r = wm + m * 16 + lr;
            int p = ((lkg + (r >> 2)) & 3) ^ (r & 3);
            bf16x8 af = *(const bf16x8*)&As[cur][(r * 4 + p) * 8];
            #pragma unroll
            for (int n = 0; n < 2; ++n)
                acc[m][n] = __builtin_amdgcn_mfma_f32_16x16x32_bf16(
                    af, bfr[n], acc[m][n], 0, 0, 0);
        }
        __syncthreads();
    }

    float knv[2];
    #pragma unroll
    for (int n = 0; n < 2; ++n) {
        int gcol = bn + wn + n * 16 + lr;
        knv[n] = (gcol < N) ? knrm[gcol] : 0.f;
    }
    if (MODE == 1) {
        #pragma unroll
        for (int m = 0; m < 4; ++m) {
            #pragma unroll
            for (int n = 0; n < 2; ++n) {
                int gcol = bn + wn + n * 16 + lr;
                if (gcol >= N) continue;
                #pragma unroll
                for (int r = 0; r < 4; ++r) {
                    int grow = bm + wm + m * 16 + lkg * 4 + r;
                    scores[(size_t)grow * PCHN + gcol] = knv[n] - 2.0f * acc[m][n][r];
                }
            }
        }
    } else {
        unsigned taur[16];
        #pragma unroll
        for (int m = 0; m < 4; ++m)
            #pragma unroll
            for (int r = 0; r < 4; ++r)
                taur[m * 4 + r] = tau32[bm + wm + m * 16 + lkg * 4 + r];
        #pragma unroll
        for (int m = 0; m < 4; ++m) {
            #pragma unroll
            for (int r = 0; r < 4; ++r) {
                int grow = bm + wm + m * 16 + lkg * 4 + r;
                #pragma unroll
                for (int n = 0; n < 2; ++n) {
                    int gcol = bn + wn + n * 16 + lr;
                    bool pass = false;
                    unsigned key = 0;
                    if (gcol < N) {
                        key = fkey(knv[n] - 2.0f * acc[m][n][r]);
                        pass = key <= taur[m * 4 + r];
                    }
                    u64 bal = __ballot(pass);
                    unsigned g16 = (unsigned)((bal >> (lkg * 16)) & 0xFFFFu);
                    if (g16) {
                        int cntp = __popc(g16);
                        int first = __ffs(g16) - 1;
                        int base = 0;
                        if (lr == first) base = atomicAdd(&svcnt[grow * SVSTRIDE], cntp);
                        base = __shfl(base, lkg * 16 + first);
                        if (pass) {
                            int p = base + __popc(g16 & ((1u << lr) - 1u));
                            if (p < SCAP)
                                surv[(size_t)grow * SCAP + p] =
                                    ((u64)key << 32) | (unsigned)(n0 + gcol);
                        }
                    }
                }
            }
        }
    }
}

// ---------- converts ----------
__global__ __launch_bounds__(256) void cvt_transpose(
    const float* __restrict__ W, unsigned short* __restrict__ Wt, int K, int N)
{
    int idx = blockIdx.x * 256 + threadIdx.x;
    if (idx >= K * N) return;
    int k = idx / N, n = idx % N;
    Wt[(size_t)n * K + k] = f2b(W[idx]);
}
__global__ __launch_bounds__(256) void cvt_split_transpose(
    const float* __restrict__ W, unsigned short* __restrict__ Wh,
    unsigned short* __restrict__ Wl, int K, int N)
{
    int idx = blockIdx.x * 256 + threadIdx.x;
    if (idx >= K * N) return;
    int k = idx / N, n = idx % N;
    float v = W[idx];
    unsigned short h = f2b(v);
    Wh[(size_t)n * K + k] = h;
    Wl[(size_t)n * K + k] = f2b(v - b2f(h));
}

// ---------- row norms ----------
__global__ __launch_bounds__(256) void rownorms(const float* __restrict__ ki,
                                                float* __restrict__ out, int M)
{
    int n = blockIdx.x * 4 + (threadIdx.x >> 6);
    int lane = threadIdx.x & 63;
    if (n >= M) return;
    float4 v = *(const float4*)(ki + (size_t)n * D_MAIN + lane * 4);
    float s = v.x * v.x + v.y * v.y + v.z * v.z + v.w * v.w;
    s = wsum(s);
    if (lane == 0) out[n] = s;
}

// ---------- bitonic sorts ----------
__device__ void bitonic512(u64* s, int t)
{
    for (int k = 2; k <= 512; k <<= 1) {
        for (int j = k >> 1; j > 0; j >>= 1) {
            __syncthreads();
            #pragma unroll
            for (int q = 0; q < 2; ++q) {
                int l = t + q * 256;
                int p = l ^ j;
                if (p > l) {
                    u64 a = s[l], bb = s[p];
                    bool up = ((l & k) == 0);
                    if ((a > bb) == up) { s[l] = bb; s[p] = a; }
                }
            }
        }
    }
    __syncthreads();
}
__device__ void bitonic1024(u64* s, int t)
{
    for (int k = 2; k <= 1024; k <<= 1) {
        for (int j = k >> 1; j > 0; j >>= 1) {
            __syncthreads();
            #pragma unroll
            for (int q = 0; q < 4; ++q) {
                int l = t + q * 256;
                int p = l ^ j;
                if (p > l) {
                    u64 a = s[l], bb = s[p];
                    bool up = ((l & k) == 0);
                    if ((a > bb) == up) { s[l] = bb; s[p] = a; }
                }
            }
        }
    }
    __syncthreads();
}

// ---------- pilot: exact top-128 of pilot scores + tau ----------
__global__ __launch_bounds__(256) void pilot_select(
    const float* __restrict__ scores, u64* __restrict__ pilotbuf,
    unsigned* __restrict__ tau32)
{
    int b = blockIdx.x, t = threadIdx.x;
    int lane = t & 63;
    __shared__ u64 s[1024];
    __shared__ int cnt;
    __shared__ u64 tauf;
    const float* row = scores + (size_t)b * PCHN;
    #pragma unroll
    for (int q = 0; q < 4; ++q) {
        int n = t + q * 256;
        s[n] = ((u64)fkey(row[n]) << 32) | (unsigned)n;
    }
    __syncthreads();
    bitonic1024(s, t);
    if (t == 0) { cnt = 128; tauf = s[127]; }
    #pragma unroll
    for (int q = 0; q < 4; ++q) { int n = t + q * 256; if (n >= 128) s[n] = ~0ULL; }
    __syncthreads();
    for (int base = 1024; base < PCHN; base += 1024) {
        u64 tau = tauf;
        int n = base + t * 4;
        float4 v = *(const float4*)(row + n);
        #pragma unroll
        for (int j = 0; j < 4; ++j) {
            float x = (&v.x)[j];
            u64 e = ((u64)fkey(x) << 32) | (unsigned)(n + j);
            bool pass = e < tau;
            u64 m = __ballot(pass);
            if (m) {
                int bs = 0;
                if (lane == 0) bs = atomicAdd(&cnt, (int)__popcll(m));
                bs = __shfl(bs, 0);
                if (pass) {
                    int p = bs + (int)__popcll(m & ((1ULL << lane) - 1ULL));
                    if (p < 1024) s[p] = e;
                }
            }
        }
        __syncthreads();
        if (cnt > 512) {
            bitonic1024(s, t);
            if (t == 0) { cnt = 128; tauf = s[127]; }
            #pragma unroll
            for (int q = 0; q < 4; ++q) { int n2 = t + q * 256; if (n2 >= 128) s[n2] = ~0ULL; }
        }
        __syncthreads();
    }
    bitonic1024(s, t);
    if (t < 128) pilotbuf[(size_t)b * 128 + t] = s[t];
    if (t == 0) tau32[b] = (unsigned)(s[127] >> 32);
}

// ---------- init survivors from pilot ----------
__global__ __launch_bounds__(128) void init_surv(
    const u64* __restrict__ pilotbuf, u64* __restrict__ surv, int* __restrict__ svcnt)
{
    int b = blockIdx.x, t = threadIdx.x;
    surv[(size_t)b * SCAP + t] = pilotbuf[(size_t)b * 128 + t];
    if (t == 0) svcnt[b * SVSTRIDE] = 128;
}

// ---------- final: exact top-128 of survivor set -> refI ----------
__global__ __launch_bounds__(256) void final_select(
    const u64* __restrict__ surv, const int* __restrict__ svcnt,
    int* __restrict__ refI)
{
    int b = blockIdx.x, t = threadIdx.x;
    int lane = t & 63;
    __shared__ u64 s[1024];
    __shared__ int cnt;
    __shared__ u64 tauf;
    int total = svcnt[b * SVSTRIDE]; if (total > SCAP) total = SCAP;
    const u64* rowp = surv + (size_t)b * SCAP;
    #pragma unroll
    for (int q = 0; q < 4; ++q) {
        int n = t + q * 256;
        s[n] = (n < total) ? rowp[n] : ~0ULL;
    }
    __syncthreads();
    bitonic1024(s, t);
    if (t == 0) { cnt = 128; tauf = s[127]; }
    #pragma unroll
    for (int q = 0; q < 4; ++q) { int n = t + q * 256; if (n >= 128) s[n] = ~0ULL; }
    __syncthreads();
    for (int base = 1024; base < total; base += 1024) {
        u64 tau = tauf;
        int n = base + t * 4;
        #pragma unroll
        for (int j = 0; j < 4; ++j) {
            u64 e = (n + j < total) ? rowp[n + j] : ~0ULL;
            bool pass = e < tau;
            u64 m = __ballot(pass);
            if (m) {
                int bs = 0;
                if (lane == 0) bs = atomicAdd(&cnt, (int)__popcll(m));
                bs = __shfl(bs, 0);
                if (pass) {
                    int p = bs + (int)__popcll(m & ((1ULL << lane) - 1ULL));
                    if (p < 1024) s[p] = e;
                }
            }
        }
        __syncthreads();
        if (cnt > 512) {
            bitonic1024(s, t);
            if (t == 0) { cnt = 128; tauf = s[127]; }
            #pragma unroll
            for (int q = 0; q < 4; ++q) { int n2 = t + q * 256; if (n2 >= 128) s[n2] = ~0ULL; }
        }
        __syncthreads();
    }
    bitonic1024(s, t);
    if (t < RKEEP) refI[b * RKEEP + t] = (int)(unsigned)(s[t] & 0xffffffffULL);
}

// ---------- exact fp32 refine of RKEEP survivors -> top-96 + S ----------
__global__ __launch_bounds__(256) void refine(
    const float* __restrict__ kmat, const float* __restrict__ kiall,
    const float* __restrict__ knorm, const float* __restrict__ kinorm,
    const int* __restrict__ refI, int* __restrict__ Ifin, float* __restrict__ Sbuf)
{
    int b = blockIdx.x, t = threadIdx.x;
    int w = t >> 6, lane = t & 63;
    __shared__ float kk[256];
    __shared__ u64 s[512];
    kk[t] = kmat[b * D_MAIN + t];
    s[t] = ~0ULL; s[t + 256] = ~0ULL;
    __syncthreads();
    float kn = knorm[b];
    for (int sv = w; sv < RKEEP; sv += 4) {
        int n = refI[b * RKEEP + sv];
        float4 a = *(const float4*)&kk[lane * 4];
        float4 bb = ((const float4*)(kiall + (size_t)n * D_MAIN))[lane];
        float d = a.x * bb.x + a.y * bb.y + a.z * bb.z + a.w * bb.w;
        d = wsum(d);
        if (lane == 0) {
            float d2 = kn + kinorm[n] - 2.f * d;
            s[sv] = ((u64)fkey(d2) << 32) | (unsigned)n;
        }
    }
    __syncthreads();
    bitonic512(s, t);
    if (t < CTX) {
        u64 e = s[t];
        Ifin[b * CTX + t] = (int)(unsigned)(e & 0xffffffffULL);
        Sbuf[b * CTX + t] = finv((unsigned)(e >> 32));
    }
}

// ---------- gather diff (bf16) ----------
__global__ __launch_bounds__(64) void gather_diff_bf(
    const float* __restrict__ kmat, const float* __restrict__ kiall,
    const int* __restrict__ I, unsigned short* __restrict__ diffb)
{
    int bc = blockIdx.x;
    int b = bc / CTX;
    int t = threadIdx.x;
    int idx = I[bc];
    float4 kv = ((const float4*)(kmat + (size_t)b * D_MAIN))[t];
    float4 iv = ((const float4*)(kiall + (size_t)idx * D_MAIN))[t];
    ushort4 u;
    u.x = f2b(kv.x - iv.x); u.y = f2b(kv.y - iv.y);
    u.z = f2b(kv.z - iv.z); u.w = f2b(kv.w - iv.w);
    ((ushort4*)(diffb + (size_t)bc * D_MAIN))[t] = u;
}

// ---------- softmax over 96 ----------
__global__ __launch_bounds__(128) void softmax96(const float* __restrict__ S,
                                                 float* __restrict__ w)
{
    int b = blockIdx.x, t = threadIdx.x;
    __shared__ float rm[2], rs[2];
    float v = (t < CTX) ? S[b * CTX + t] : -__builtin_inff();
    float m = wmax(v);
    if ((t & 63) == 0) rm[t >> 6] = m;
    __syncthreads();
    m = fmaxf(rm[0], rm[1]);
    float e = (t < CTX) ? expf(v - m) : 0.f;
    float ss = wsum(e);
    if ((t & 63) == 0) rs[t >> 6] = ss;
    __syncthreads();
    float Z = rs[0] + rs[1];
    if (t < CTX) w[b * CTX + t] = e / Z;
}

// ---------- aggregation ----------
__global__ __launch_bounds__(256) void aggregate(
    const float* __restrict__ w, const int* __restrict__ I,
    const int* __restrict__ cand_y, const float* __restrict__ Yemb,
    const float* __restrict__ mlp, const float* __restrict__ x,
    float* __restrict__ x2)
{
    int b = blockIdx.x, t = threadIdx.x;
    __shared__ float ws[CTX];
    __shared__ int lab[CTX];
    if (t < CTX) {
        ws[t] = w[b * CTX + t];
        lab[t] = cand_y[I[b * CTX + t]];
    }
    __syncthreads();
    float acc = 0.f;
    for (int c = 0; c < CTX; ++c) {
        acc += ws[c] * (Yemb[lab[c] * D_MAIN + t] + mlp[((size_t)b * CTX + c) * D_MAIN + t]);
    }
    x2[b * D_MAIN + t] = x[b * D_MAIN + t] + acc;
}

// ---------- predictor block + head ----------
__global__ __launch_bounds__(256) void predictor_head(
    const float* __restrict__ x2,
    const float* __restrict__ lns, const float* __restrict__ lnb,
    const float* __restrict__ W1, const float* __restrict__ b1,
    const float* __restrict__ W2, const float* __restrict__ b2,
    const float* __restrict__ plns, const float* __restrict__ plnb,
    const float* __restrict__ PW, const float* __restrict__ Pb,
    float* __restrict__ out)
{
    int b = blockIdx.x, t = threadIdx.x;
    __shared__ float ln1[256], hdn[512], red[4];
    float xv = x2[b * D_MAIN + t];
    float s1 = blockSum256(xv, red);
    float s2 = blockSum256(xv * xv, red);
    float mean = s1 * (1.f / 256.f);
    float var = s2 * (1.f / 256.f) - mean * mean;
    float rstd = rsqrtf(var + 1e-5f);
    ln1[t] = (xv - mean) * rstd * lns[t] + lnb[t];
    __syncthreads();
    #pragma unroll
    for (int rep = 0; rep < 2; ++rep) {
        int j = t + rep * 256;
        float a = b1[j];
        for (int i = 0; i < 256; ++i) a += ln1[i] * W1[i * D_INT + j];
        hdn[j] = fmaxf(a, 0.f);
    }
    __syncthreads();
    float a3 = b2[t];
    for (int i = 0; i < 512; ++i) a3 += hdn[i] * W2[i * D_MAIN + t];
    float x3 = xv + a3;
    float s3 = blockSum256(x3, red);
    float s4 = blockSum256(x3 * x3, red);
    float m2 = s3 * (1.f / 256.f);
    float v2 = s4 * (1.f / 256.f) - m2 * m2;
    float r2 = rsqrtf(v2 + 1e-5f);
    float rv = fmaxf((x3 - m2) * r2 * plns[t] + plnb[t], 0.f);
    __syncthreads();
    ln1[t] = rv;
    __syncthreads();
    if (t < N_CLS) {
        float a = Pb[t];
        for (int i = 0; i < 256; ++i) a += ln1[i] * PW[i * N_CLS + t];
        out[b * N_CLS + t] = a;
    }
}

// ---------- host-side launch ----------
extern "C" void kernel_launch(void* const* d_in, const int* in_sizes, int n_in,
                              void* d_out, int out_size, void* d_ws, size_t ws_size,
                              hipStream_t stream)
{
    (void)in_sizes; (void)n_in; (void)out_size; (void)ws_size;
    const float* x_num   = (const float*)d_in[0];
    const float* cand    = (const float*)d_in[1];
    const int*   cand_y  = (const int*)d_in[2];
    const float* W_lin   = (const float*)d_in[4];
    const float* b_lin   = (const float*)d_in[5];
    const float* W_K     = (const float*)d_in[6];
    const float* b_K     = (const float*)d_in[7];
    const float* Y_emb   = (const float*)d_in[8];
    const float* T_W1    = (const float*)d_in[9];
    const float* T_b1    = (const float*)d_in[10];
    const float* T_W2    = (const float*)d_in[11];
    const float* bp_ln_s = (const float*)d_in[12];
    const float* bp_ln_b = (const float*)d_in[13];
    const float* bp_W1   = (const float*)d_in[14];
    const float* bp_b1   = (const float*)d_in[15];
    const float* bp_W2   = (const float*)d_in[16];
    const float* bp_b2   = (const float*)d_in[17];
    const float* P_ln_s  = (const float*)d_in[18];
    const float* P_ln_b  = (const float*)d_in[19];
    const float* P_W     = (const float*)d_in[20];
    const float* P_b     = (const float*)d_in[21];
    float* outp = (float*)d_out;

    char* ws = (char*)d_ws;
    float* kiall  = (float*)(ws + 0);
    unsigned short* hidden = (unsigned short*)(ws + 0);
    unsigned short* ki_bf = (unsigned short*)(ws + 102400000);
    unsigned short* diffb = (unsigned short*)(ws + 102400000);
    float* mlpbuf = (float*)(ws + 102400000);
    float* scores = (float*)(ws + 153600000);
    u64*   surv   = (u64*)(ws + 153600000);
    const size_t T = 204800000;
    float* xbuf   = (float*)(ws + T + 0);
    float* kbuf   = (float*)(ws + T + 1048576);
    float* x2buf  = (float*)(ws + T + 2097152);
    float* knorm  = (float*)(ws + T + 3145728);
    float* kinorm = (float*)(ws + T + 3149824);
    unsigned short* k_bf = (unsigned short*)(ws + T + 3551232);
    float* Wf     = (float*)(ws + T + 4075520);            // 128x256 f32
    unsigned short* WfH = (unsigned short*)(ws + T + 4206592);  // 256x128 bf16
    unsigned short* WfL = (unsigned short*)(ws + T + 4272128);
    float* bfused = (float*)(ws + T + 4337664);            // 256 f32
    unsigned short* W1t  = (unsigned short*)(ws + T + 4468736);
    unsigned short* W2t  = (unsigned short*)(ws + T + 4730880);
    float* Sbuf   = (float*)(ws + T + 4993024);
    float* wbuf   = (float*)(ws + T + 5386240);
    int*   refI   = (int*)(ws + T + 5779456);
    int*   Ifin   = (int*)(ws + T + 6303744);
    u64*   pilotbuf = (u64*)(ws + T + 6696960);
    unsigned* tau32 = (unsigned*)(ws + T + 7745536);
    int*   svcnt  = (int*)(ws + T + 7749632);

    // 1. batch encode (exact fp32, fused bf16 emit)
    encode_batch<<<B_ROWS, 256, 0, stream>>>(x_num, W_lin, b_lin, W_K, b_K,
                                             xbuf, kbuf, knorm, k_bf);
    // 2. fused encoder weights (fp32): Wf = Wl@Wk, bf = bl@Wk + bk; split to bf16
    fuse_weights<<<129, 256, 0, stream>>>(W_lin, W_K, b_lin, b_K, Wf, bfused);
    cvt_split_transpose<<<128, 256, 0, stream>>>(Wf, WfH, WfL, N_FEAT, D_MAIN);
    cvt_transpose<<<512, 256, 0, stream>>>(T_W1, W1t, D_MAIN, D_INT);
    cvt_transpose<<<512, 256, 0, stream>>>(T_W2, W2t, D_INT, D_MAIN);
    // 3. candidate keys via ONE fused split-bf16 GEMM (fp32-accurate), K=128
    gemm_split3<true><<<dim3(782, 4), 256, 0, stream>>>(
        cand, WfH, WfL, bfused, kiall, ki_bf, N_CAND, D_MAIN, N_FEAT);
    // 4. candidate norms
    rownorms<<<25000, 256, 0, stream>>>(kiall, kinorm, N_CAND);
    // 5. pilot: screen first PCHN candidates, exact top-128 + tau
    screen_gemm<1><<<dim3(8, PCHN / 64), 256, 0, stream>>>(
        k_bf, ki_bf, scores, PCHN, 0, kinorm, nullptr, nullptr, nullptr);
    pilot_select<<<B_ROWS, 256, 0, stream>>>(scores, pilotbuf, tau32);
    init_surv<<<B_ROWS, 128, 0, stream>>>(pilotbuf, surv, svcnt);
    // 6. fused screen+filter over remaining candidates
    screen_gemm<2><<<dim3(8, (N2 + 63) / 64), 256, 0, stream>>>(
        k_bf, ki_bf + (size_t)PCHN * D_MAIN, nullptr, N2, PCHN,
        kinorm + PCHN, tau32, svcnt, surv);
    // 7. final exact top-128 of survivors -> refI
    final_select<<<B_ROWS, 256, 0, stream>>>(surv, svcnt, refI);
    // 8. exact fp32 refine -> top-96 + S
    refine<<<B_ROWS, 256, 0, stream>>>(kbuf, kiall, knorm, kinorm, refI, Ifin, Sbuf);
    // 9. softmax weights
    softmax96<<<B_ROWS, 128, 0, stream>>>(Sbuf, wbuf);
    // 10. gather diff (bf16)
    gather_diff_bf<<<B_ROWS * CTX, 64, 0, stream>>>(kbuf, kiall, Ifin, diffb);
    // 11. T-MLP on MFMA (128x64 tiles, dbuf)
    gemm_bf16<true, true><<<dim3(768, 8), 256, 0, stream>>>(
        diffb, W1t, T_b1, hidden, B_ROWS * CTX, D_INT, D_MAIN);
    gemm_bf16<false, false><<<dim3(768, 4), 256, 0, stream>>>(
        hidden, W2t, nullptr, mlpbuf, B_ROWS * CTX, D_MAIN, D_INT);
    // 12. aggregate
    aggregate<<<B_ROWS, 256, 0, stream>>>(wbuf, Ifin, cand_y, Y_emb, mlpbuf,
                                          xbuf, x2buf);
    // 13. predictor + head
    predictor_head<<<B_ROWS, 256, 0, stream>>>(x2buf, bp_ln_s, bp_ln_b,
                                               bp_W1, bp_b1, bp_W2, bp_b2,
                                               P_ln_s, P_ln_b, P_W, P_b, outp);
}

// Round 16
// 797.643 us; speedup vs baseline: 1.1657x; 1.1137x over previous
//
#include <hip/hip_runtime.h>
#include <hip/hip_bf16.h>

#define B_ROWS   1024
#define N_FEAT   128
#define D_MAIN   256
#define D_INT    512
#define N_CAND   100000
#define CTX      96
#define N_CLS    10
#define PCHN     8192    // pilot chunk size (measured optimum: tau tightness vs pilot cost)
#define N2       91808   // remaining candidates (fused filter path)
#define RKEEP    128     // refine set size
#define SCAP     6144    // survivor cap per row
#define SVSTRIDE 16      // svcnt padded to one counter per 64B line

typedef __attribute__((ext_vector_type(8))) short bf16x8;
typedef __attribute__((ext_vector_type(4))) float f32x4;
typedef unsigned long long u64;

// ---------- helpers ----------
__device__ __forceinline__ float wsum(float v) {
    #pragma unroll
    for (int o = 32; o > 0; o >>= 1) v += __shfl_down(v, o);
    return v;
}
__device__ __forceinline__ float wmax(float v) {
    #pragma unroll
    for (int o = 32; o > 0; o >>= 1) v = fmaxf(v, __shfl_down(v, o));
    return v;
}
__device__ __forceinline__ float blockSum256(float v, float* red) {
    int t = threadIdx.x;
    float s = wsum(v);
    if ((t & 63) == 0) red[t >> 6] = s;
    __syncthreads();
    s = red[0] + red[1] + red[2] + red[3];
    __syncthreads();
    return s;
}
__device__ __forceinline__ float b2f(unsigned short u) {
    return __uint_as_float(((unsigned)u) << 16);
}
__device__ __forceinline__ unsigned short f2b(float f) {
    unsigned x = __float_as_uint(f);
    return (unsigned short)((x + 0x7fff + ((x >> 16) & 1)) >> 16);
}
__device__ __forceinline__ unsigned fkey(float f) {
    unsigned u = __float_as_uint(f);
    return u ^ ((((int)u >> 31)) | 0x80000000u);
}
__device__ __forceinline__ float finv(unsigned k) {
    unsigned u = (k & 0x80000000u) ? (k ^ 0x80000000u) : ~k;
    return __uint_as_float(u);
}
#define SPLIT1(x, hv, lv) { unsigned short _h = f2b(x); hv = (short)_h; lv = (short)f2b((x) - b2f(_h)); }

// ---------- K1: batch encode (also emits bf16 copy of k) ----------
__global__ __launch_bounds__(256) void encode_batch(
    const float* __restrict__ xn, const float* __restrict__ Wl, const float* __restrict__ bl,
    const float* __restrict__ Wk, const float* __restrict__ bk,
    float* __restrict__ xout, float* __restrict__ kout, float* __restrict__ knorm,
    unsigned short* __restrict__ kbf)
{
    int b = blockIdx.x, t = threadIdx.x;
    __shared__ float si[128], sx[256], red[4];
    if (t < 128) si[t] = xn[b * N_FEAT + t];
    __syncthreads();
    float a = bl[t];
    for (int i = 0; i < 128; ++i) a += si[i] * Wl[i * D_MAIN + t];
    xout[b * D_MAIN + t] = a;
    sx[t] = a;
    __syncthreads();
    float a2 = bk[t];
    for (int i = 0; i < 256; ++i) a2 += sx[i] * Wk[i * D_MAIN + t];
    kout[b * D_MAIN + t] = a2;
    kbf[b * D_MAIN + t] = f2b(a2);
    float s = blockSum256(a2 * a2, red);
    if (t == 0) knorm[b] = s;
}

// ---------- fused encoder weights: Wf = Wl@Wk (fp32), bf = bl@Wk + bk ----------
__global__ __launch_bounds__(256) void fuse_weights(
    const float* __restrict__ Wl, const float* __restrict__ Wk,
    const float* __restrict__ bl, const float* __restrict__ bk,
    float* __restrict__ Wf, float* __restrict__ bf)
{
    int i = blockIdx.x, t = threadIdx.x;
    __shared__ float row[256];
    if (i < 128) {
        row[t] = Wl[i * D_MAIN + t];
        __syncthreads();
        float a = 0.f;
        for (int k = 0; k < 256; ++k) a += row[k] * Wk[k * D_MAIN + t];
        Wf[i * D_MAIN + t] = a;
    } else {
        row[t] = bl[t];
        __syncthreads();
        float a = bk[t];
        for (int k = 0; k < 256; ++k) a += row[k] * Wk[k * D_MAIN + t];
        bf[t] = a;
    }
}

// ---------- split-bf16 fp32-accurate GEMM, 128x64 tile, acc[4][2] ----------
template<bool WRITE_BF16>
__global__ __launch_bounds__(256) void gemm_split3(
    const float* __restrict__ A,
    const unsigned short* __restrict__ Bh,
    const unsigned short* __restrict__ Bl,
    const float* __restrict__ bias,
    float* __restrict__ Cf,
    unsigned short* __restrict__ Cbf,
    int M, int N, int K)
{
    __shared__ __align__(16) short Ash[4096], Asl[4096];   // 128 x 32
    __shared__ __align__(16) short Bsh[2048], Bsl[2048];   // 64 x 32
    const int t = threadIdx.x;
    const int bm = blockIdx.x * 128, bn = blockIdx.y * 64;
    const int wave = t >> 6, lane = t & 63;
    const int wm = (wave >> 1) * 64, wn = (wave & 1) * 32;
    const int lr = lane & 15, lkg = lane >> 4;
    f32x4 acc[4][2] = {};
    const int row0 = t >> 2, kg0 = t & 3;     // row0 in 0..63
    const int row1 = row0 + 64;
    const int p0 = ((kg0 + (row0 >> 2)) & 3) ^ (row0 & 3);
    const int p1 = ((kg0 + (row1 >> 2)) & 3) ^ (row1 & 3);
    const int gm0 = bm + row0, gm1 = bm + row1;
    const int nB = bn + row0;

    float4 u00, u01, u10, u11;
    bf16x8 bh0, bl0;
    auto prefetch = [&](int kq) {
        float4 z4 = make_float4(0.f, 0.f, 0.f, 0.f); bf16x8 z = {};
        u00 = z4; u01 = z4; u10 = z4; u11 = z4;
        bh0 = z; bl0 = z;
        if (gm0 < M) {
            const float* ap = A + (size_t)gm0 * K + kq + kg0 * 8;
            u00 = *(const float4*)ap; u01 = *(const float4*)(ap + 4);
        }
        if (gm1 < M) {
            const float* ap = A + (size_t)gm1 * K + kq + kg0 * 8;
            u10 = *(const float4*)ap; u11 = *(const float4*)(ap + 4);
        }
        if (nB < N) {
            bh0 = *(const bf16x8*)(Bh + (size_t)nB * K + kq + kg0 * 8);
            bl0 = *(const bf16x8*)(Bl + (size_t)nB * K + kq + kg0 * 8);
        }
    };
    prefetch(0);

    for (int k0 = 0; k0 < K; k0 += 32) {
        bf16x8 a0h, a0l, a1h, a1l;
        SPLIT1(u00.x, a0h[0], a0l[0]); SPLIT1(u00.y, a0h[1], a0l[1]);
        SPLIT1(u00.z, a0h[2], a0l[2]); SPLIT1(u00.w, a0h[3], a0l[3]);
        SPLIT1(u01.x, a0h[4], a0l[4]); SPLIT1(u01.y, a0h[5], a0l[5]);
        SPLIT1(u01.z, a0h[6], a0l[6]); SPLIT1(u01.w, a0h[7], a0l[7]);
        SPLIT1(u10.x, a1h[0], a1l[0]); SPLIT1(u10.y, a1h[1], a1l[1]);
        SPLIT1(u10.z, a1h[2], a1l[2]); SPLIT1(u10.w, a1h[3], a1l[3]);
        SPLIT1(u11.x, a1h[4], a1l[4]); SPLIT1(u11.y, a1h[5], a1l[5]);
        SPLIT1(u11.z, a1h[6], a1l[6]); SPLIT1(u11.w, a1h[7], a1l[7]);
        __syncthreads();
        *(bf16x8*)&Ash[(row0 * 4 + p0) * 8] = a0h;
        *(bf16x8*)&Asl[(row0 * 4 + p0) * 8] = a0l;
        *(bf16x8*)&Ash[(row1 * 4 + p1) * 8] = a1h;
        *(bf16x8*)&Asl[(row1 * 4 + p1) * 8] = a1l;
        *(bf16x8*)&Bsh[(row0 * 4 + p0) * 8] = bh0;
        *(bf16x8*)&Bsl[(row0 * 4 + p0) * 8] = bl0;
        if (k0 + 32 < K) prefetch(k0 + 32);
        __syncthreads();
        bf16x8 bfh[2], bfl[2];
        #pragma unroll
        for (int n = 0; n < 2; ++n) {
            int r = wn + n * 16 + lr;
            int p = ((lkg + (r >> 2)) & 3) ^ (r & 3);
            bfh[n] = *(const bf16x8*)&Bsh[(r * 4 + p) * 8];
            bfl[n] = *(const bf16x8*)&Bsl[(r * 4 + p) * 8];
        }
        #pragma unroll
        for (int m = 0; m < 4; ++m) {
            int r = wm + m * 16 + lr;
            int p = ((lkg + (r >> 2)) & 3) ^ (r & 3);
            bf16x8 ah = *(const bf16x8*)&Ash[(r * 4 + p) * 8];
            bf16x8 al = *(const bf16x8*)&Asl[(r * 4 + p) * 8];
            #pragma unroll
            for (int n = 0; n < 2; ++n) {
                acc[m][n] = __builtin_amdgcn_mfma_f32_16x16x32_bf16(al, bfh[n], acc[m][n], 0, 0, 0);
                acc[m][n] = __builtin_amdgcn_mfma_f32_16x16x32_bf16(ah, bfl[n], acc[m][n], 0, 0, 0);
                acc[m][n] = __builtin_amdgcn_mfma_f32_16x16x32_bf16(ah, bfh[n], acc[m][n], 0, 0, 0);
            }
        }
    }
    #pragma unroll
    for (int m = 0; m < 4; ++m) {
        #pragma unroll
        for (int n = 0; n < 2; ++n) {
            f32x4 a = acc[m][n];
            int gcol = bn + wn + n * 16 + lr;
            if (gcol >= N) continue;
            float bv = bias[gcol];
            #pragma unroll
            for (int r = 0; r < 4; ++r) {
                int grow = bm + wm + m * 16 + lkg * 4 + r;
                if (grow >= M) continue;
                float v = a[r] + bv;
                Cf[(size_t)grow * N + gcol] = v;
                if (WRITE_BF16) Cbf[(size_t)grow * N + gcol] = f2b(v);
            }
        }
    }
}

// ---------- T-MLP bf16 GEMM: 128x64 tile, acc[4][2], dbuf LDS (1 barrier/K-step) ----------
template<bool RELU, bool OUT_BF16>
__global__ __launch_bounds__(256) void gemm_bf16(
    const unsigned short* __restrict__ A,
    const unsigned short* __restrict__ Bt,
    const float* __restrict__ bias,
    void* __restrict__ C, int M, int N, int K)
{
    __shared__ __align__(16) short As[2][4096];
    __shared__ __align__(16) short Bs[2][2048];
    const int t = threadIdx.x;
    const int bm = blockIdx.x * 128, bn = blockIdx.y * 64;
    const int wave = t >> 6, lane = t & 63;
    const int wm = (wave >> 1) * 64, wn = (wave & 1) * 32;
    const int lr = lane & 15, lkg = lane >> 4;
    f32x4 acc[4][2] = {};
    const int row0 = t >> 2, kg0 = t & 3;
    const int row1 = row0 + 64;
    const int p0 = ((kg0 + (row0 >> 2)) & 3) ^ (row0 & 3);
    const int p1 = ((kg0 + (row1 >> 2)) & 3) ^ (row1 & 3);
    const int gm0 = bm + row0, gm1 = bm + row1;
    const int nB = bn + row0;

    bf16x8 a0, a1, b0;
    auto prefetch = [&](int kq) {
        bf16x8 z = {};
        a0 = z; a1 = z; b0 = z;
        if (gm0 < M) a0 = *(const bf16x8*)(A + (size_t)gm0 * K + kq + kg0 * 8);
        if (gm1 < M) a1 = *(const bf16x8*)(A + (size_t)gm1 * K + kq + kg0 * 8);
        if (nB < N) b0 = *(const bf16x8*)(Bt + (size_t)nB * K + kq + kg0 * 8);
    };
    prefetch(0);
    *(bf16x8*)&As[0][(row0 * 4 + p0) * 8] = a0;
    *(bf16x8*)&As[0][(row1 * 4 + p1) * 8] = a1;
    *(bf16x8*)&Bs[0][(row0 * 4 + p0) * 8] = b0;
    if (32 < K) prefetch(32);
    __syncthreads();

    for (int k0 = 0; k0 < K; k0 += 32) {
        const int cur = (k0 >> 5) & 1;
        if (k0 + 32 < K) {
            const int nxt = cur ^ 1;
            *(bf16x8*)&As[nxt][(row0 * 4 + p0) * 8] = a0;
            *(bf16x8*)&As[nxt][(row1 * 4 + p1) * 8] = a1;
            *(bf16x8*)&Bs[nxt][(row0 * 4 + p0) * 8] = b0;
            if (k0 + 64 < K) prefetch(k0 + 64);
        }
        bf16x8 bfr[2];
        #pragma unroll
        for (int n = 0; n < 2; ++n) {
            int r = wn + n * 16 + lr;
            int p = ((lkg + (r >> 2)) & 3) ^ (r & 3);
            bfr[n] = *(const bf16x8*)&Bs[cur][(r * 4 + p) * 8];
        }
        #pragma unroll
        for (int m = 0; m < 4; ++m) {
            int r = wm + m * 16 + lr;
            int p = ((lkg + (r >> 2)) & 3) ^ (r & 3);
            bf16x8 af = *(const bf16x8*)&As[cur][(r * 4 + p) * 8];
            #pragma unroll
            for (int n = 0; n < 2; ++n)
                acc[m][n] = __builtin_amdgcn_mfma_f32_16x16x32_bf16(
                    af, bfr[n], acc[m][n], 0, 0, 0);
        }
        __syncthreads();
    }
    #pragma unroll
    for (int m = 0; m < 4; ++m) {
        #pragma unroll
        for (int n = 0; n < 2; ++n) {
            f32x4 a = acc[m][n];
            int gcol = bn + wn + n * 16 + lr;
            if (gcol >= N) continue;
            float bv = bias ? bias[gcol] : 0.f;
            #pragma unroll
            for (int r = 0; r < 4; ++r) {
                int grow = bm + wm + m * 16 + lkg * 4 + r;
                if (grow >= M) continue;
                float v = a[r] + bv;
                if (RELU) v = fmaxf(v, 0.f);
                if (OUT_BF16)
                    ((unsigned short*)C)[(size_t)grow * N + gcol] = f2b(v);
                else
                    ((float*)C)[(size_t)grow * N + gcol] = v;
            }
        }
    }
}

// ---------- screen GEMM: 128x64 tile, acc[4][2], dbuf LDS (1 barrier/K-step) ----------
// MODE 1: write scores.  MODE 2: tau-filtered survivor append.
template<int MODE>
__global__ __launch_bounds__(256) void screen_gemm(
    const unsigned short* __restrict__ A,   // k_bf [1024,256]
    const unsigned short* __restrict__ Bt,  // ki_bf span [N,256]
    float* __restrict__ scores,
    int N, int n0,
    const float* __restrict__ knrm,
    const unsigned* __restrict__ tau32, int* __restrict__ svcnt,
    u64* __restrict__ surv)
{
    __shared__ __align__(16) short As[2][4096];
    __shared__ __align__(16) short Bs[2][2048];
    const int t = threadIdx.x;
    const int bm = blockIdx.x * 128, bn = blockIdx.y * 64;
    const int wave = t >> 6, lane = t & 63;
    const int wm = (wave >> 1) * 64, wn = (wave & 1) * 32;
    const int lr = lane & 15, lkg = lane >> 4;
    f32x4 acc[4][2] = {};
    const int row0 = t >> 2, kg0 = t & 3;
    const int row1 = row0 + 64;
    const int p0 = ((kg0 + (row0 >> 2)) & 3) ^ (row0 & 3);
    const int p1 = ((kg0 + (row1 >> 2)) & 3) ^ (row1 & 3);
    const int gm0 = bm + row0, gm1 = bm + row1;   // < 1024 always
    const int nB = bn + row0;

    bf16x8 a0, a1, b0;
    auto prefetch = [&](int kq) {
        bf16x8 z = {};
        b0 = z;
        a0 = *(const bf16x8*)(A + (size_t)gm0 * D_MAIN + kq + kg0 * 8);
        a1 = *(const bf16x8*)(A + (size_t)gm1 * D_MAIN + kq + kg0 * 8);
        if (nB < N) b0 = *(const bf16x8*)(Bt + (size_t)nB * D_MAIN + kq + kg0 * 8);
    };
    prefetch(0);
    *(bf16x8*)&As[0][(row0 * 4 + p0) * 8] = a0;
    *(bf16x8*)&As[0][(row1 * 4 + p1) * 8] = a1;
    *(bf16x8*)&Bs[0][(row0 * 4 + p0) * 8] = b0;
    prefetch(32);
    __syncthreads();

    for (int k0 = 0; k0 < D_MAIN; k0 += 32) {
        const int cur = (k0 >> 5) & 1;
        if (k0 + 32 < D_MAIN) {
            const int nxt = cur ^ 1;
            *(bf16x8*)&As[nxt][(row0 * 4 + p0) * 8] = a0;
            *(bf16x8*)&As[nxt][(row1 * 4 + p1) * 8] = a1;
            *(bf16x8*)&Bs[nxt][(row0 * 4 + p0) * 8] = b0;
            if (k0 + 64 < D_MAIN) prefetch(k0 + 64);
        }
        bf16x8 bfr[2];
        #pragma unroll
        for (int n = 0; n < 2; ++n) {
            int r = wn + n * 16 + lr;
            int p = ((lkg + (r >> 2)) & 3) ^ (r & 3);
            bfr[n] = *(const bf16x8*)&Bs[cur][(r * 4 + p) * 8];
        }
        #pragma unroll
        for (int m = 0; m < 4; ++m) {
            int r = wm + m * 16 + lr;
            int p = ((lkg + (r >> 2)) & 3) ^ (r & 3);
            bf16x8 af = *(const bf16x8*)&As[cur][(r * 4 + p) * 8];
            #pragma unroll
            for (int n = 0; n < 2; ++n)
                acc[m][n] = __builtin_amdgcn_mfma_f32_16x16x32_bf16(
                    af, bfr[n], acc[m][n], 0, 0, 0);
        }
        __syncthreads();
    }

    float knv[2];
    #pragma unroll
    for (int n = 0; n < 2; ++n) {
        int gcol = bn + wn + n * 16 + lr;
        knv[n] = (gcol < N) ? knrm[gcol] : 0.f;
    }
    if (MODE == 1) {
        #pragma unroll
        for (int m = 0; m < 4; ++m) {
            #pragma unroll
            for (int n = 0; n < 2; ++n) {
                int gcol = bn + wn + n * 16 + lr;
                if (gcol >= N) continue;
                #pragma unroll
                for (int r = 0; r < 4; ++r) {
                    int grow = bm + wm + m * 16 + lkg * 4 + r;
                    scores[(size_t)grow * PCHN + gcol] = knv[n] - 2.0f * acc[m][n][r];
                }
            }
        }
    } else {
        unsigned taur[16];
        #pragma unroll
        for (int m = 0; m < 4; ++m)
            #pragma unroll
            for (int r = 0; r < 4; ++r)
                taur[m * 4 + r] = tau32[bm + wm + m * 16 + lkg * 4 + r];
        #pragma unroll
        for (int m = 0; m < 4; ++m) {
            #pragma unroll
            for (int r = 0; r < 4; ++r) {
                int grow = bm + wm + m * 16 + lkg * 4 + r;
                #pragma unroll
                for (int n = 0; n < 2; ++n) {
                    int gcol = bn + wn + n * 16 + lr;
                    bool pass = false;
                    unsigned key = 0;
                    if (gcol < N) {
                        key = fkey(knv[n] - 2.0f * acc[m][n][r]);
                        pass = key <= taur[m * 4 + r];
                    }
                    u64 bal = __ballot(pass);
                    unsigned g16 = (unsigned)((bal >> (lkg * 16)) & 0xFFFFu);
                    if (g16) {
                        int cntp = __popc(g16);
                        int first = __ffs(g16) - 1;
                        int base = 0;
                        if (lr == first) base = atomicAdd(&svcnt[grow * SVSTRIDE], cntp);
                        base = __shfl(base, lkg * 16 + first);
                        if (pass) {
                            int p = base + __popc(g16 & ((1u << lr) - 1u));
                            if (p < SCAP)
                                surv[(size_t)grow * SCAP + p] =
                                    ((u64)key << 32) | (unsigned)(n0 + gcol);
                        }
                    }
                }
            }
        }
    }
}

// ---------- converts ----------
__global__ __launch_bounds__(256) void cvt_transpose(
    const float* __restrict__ W, unsigned short* __restrict__ Wt, int K, int N)
{
    int idx = blockIdx.x * 256 + threadIdx.x;
    if (idx >= K * N) return;
    int k = idx / N, n = idx % N;
    Wt[(size_t)n * K + k] = f2b(W[idx]);
}
__global__ __launch_bounds__(256) void cvt_split_transpose(
    const float* __restrict__ W, unsigned short* __restrict__ Wh,
    unsigned short* __restrict__ Wl, int K, int N)
{
    int idx = blockIdx.x * 256 + threadIdx.x;
    if (idx >= K * N) return;
    int k = idx / N, n = idx % N;
    float v = W[idx];
    unsigned short h = f2b(v);
    Wh[(size_t)n * K + k] = h;
    Wl[(size_t)n * K + k] = f2b(v - b2f(h));
}

// ---------- row norms ----------
__global__ __launch_bounds__(256) void rownorms(const float* __restrict__ ki,
                                                float* __restrict__ out, int M)
{
    int n = blockIdx.x * 4 + (threadIdx.x >> 6);
    int lane = threadIdx.x & 63;
    if (n >= M) return;
    float4 v = *(const float4*)(ki + (size_t)n * D_MAIN + lane * 4);
    float s = v.x * v.x + v.y * v.y + v.z * v.z + v.w * v.w;
    s = wsum(s);
    if (lane == 0) out[n] = s;
}

// ---------- bitonic sorts ----------
__device__ void bitonic512(u64* s, int t)
{
    for (int k = 2; k <= 512; k <<= 1) {
        for (int j = k >> 1; j > 0; j >>= 1) {
            __syncthreads();
            #pragma unroll
            for (int q = 0; q < 2; ++q) {
                int l = t + q * 256;
                int p = l ^ j;
                if (p > l) {
                    u64 a = s[l], bb = s[p];
                    bool up = ((l & k) == 0);
                    if ((a > bb) == up) { s[l] = bb; s[p] = a; }
                }
            }
        }
    }
    __syncthreads();
}
__device__ void bitonic1024(u64* s, int t)
{
    for (int k = 2; k <= 1024; k <<= 1) {
        for (int j = k >> 1; j > 0; j >>= 1) {
            __syncthreads();
            #pragma unroll
            for (int q = 0; q < 4; ++q) {
                int l = t + q * 256;
                int p = l ^ j;
                if (p > l) {
                    u64 a = s[l], bb = s[p];
                    bool up = ((l & k) == 0);
                    if ((a > bb) == up) { s[l] = bb; s[p] = a; }
                }
            }
        }
    }
    __syncthreads();
}

// ---------- pilot: exact top-128 of pilot scores + tau ----------
__global__ __launch_bounds__(256) void pilot_select(
    const float* __restrict__ scores, u64* __restrict__ pilotbuf,
    unsigned* __restrict__ tau32)
{
    int b = blockIdx.x, t = threadIdx.x;
    int lane = t & 63;
    __shared__ u64 s[1024];
    __shared__ int cnt;
    __shared__ u64 tauf;
    const float* row = scores + (size_t)b * PCHN;
    #pragma unroll
    for (int q = 0; q < 4; ++q) {
        int n = t + q * 256;
        s[n] = ((u64)fkey(row[n]) << 32) | (unsigned)n;
    }
    __syncthreads();
    bitonic1024(s, t);
    if (t == 0) { cnt = 128; tauf = s[127]; }
    #pragma unroll
    for (int q = 0; q < 4; ++q) { int n = t + q * 256; if (n >= 128) s[n] = ~0ULL; }
    __syncthreads();
    for (int base = 1024; base < PCHN; base += 1024) {
        u64 tau = tauf;
        int n = base + t * 4;
        float4 v = *(const float4*)(row + n);
        #pragma unroll
        for (int j = 0; j < 4; ++j) {
            float x = (&v.x)[j];
            u64 e = ((u64)fkey(x) << 32) | (unsigned)(n + j);
            bool pass = e < tau;
            u64 m = __ballot(pass);
            if (m) {
                int bs = 0;
                if (lane == 0) bs = atomicAdd(&cnt, (int)__popcll(m));
                bs = __shfl(bs, 0);
                if (pass) {
                    int p = bs + (int)__popcll(m & ((1ULL << lane) - 1ULL));
                    if (p < 1024) s[p] = e;
                }
            }
        }
        __syncthreads();
        if (cnt > 512) {
            bitonic1024(s, t);
            if (t == 0) { cnt = 128; tauf = s[127]; }
            #pragma unroll
            for (int q = 0; q < 4; ++q) { int n2 = t + q * 256; if (n2 >= 128) s[n2] = ~0ULL; }
        }
        __syncthreads();
    }
    bitonic1024(s, t);
    if (t < 128) pilotbuf[(size_t)b * 128 + t] = s[t];
    if (t == 0) tau32[b] = (unsigned)(s[127] >> 32);
}

// ---------- init survivors from pilot ----------
__global__ __launch_bounds__(128) void init_surv(
    const u64* __restrict__ pilotbuf, u64* __restrict__ surv, int* __restrict__ svcnt)
{
    int b = blockIdx.x, t = threadIdx.x;
    surv[(size_t)b * SCAP + t] = pilotbuf[(size_t)b * 128 + t];
    if (t == 0) svcnt[b * SVSTRIDE] = 128;
}

// ---------- final: exact top-128 of survivor set -> refI ----------
__global__ __launch_bounds__(256) void final_select(
    const u64* __restrict__ surv, const int* __restrict__ svcnt,
    int* __restrict__ refI)
{
    int b = blockIdx.x, t = threadIdx.x;
    int lane = t & 63;
    __shared__ u64 s[1024];
    __shared__ int cnt;
    __shared__ u64 tauf;
    int total = svcnt[b * SVSTRIDE]; if (total > SCAP) total = SCAP;
    const u64* rowp = surv + (size_t)b * SCAP;
    #pragma unroll
    for (int q = 0; q < 4; ++q) {
        int n = t + q * 256;
        s[n] = (n < total) ? rowp[n] : ~0ULL;
    }
    __syncthreads();
    bitonic1024(s, t);
    if (t == 0) { cnt = 128; tauf = s[127]; }
    #pragma unroll
    for (int q = 0; q < 4; ++q) { int n = t + q * 256; if (n >= 128) s[n] = ~0ULL; }
    __syncthreads();
    for (int base = 1024; base < total; base += 1024) {
        u64 tau = tauf;
        int n = base + t * 4;
        #pragma unroll
        for (int j = 0; j < 4; ++j) {
            u64 e = (n + j < total) ? rowp[n + j] : ~0ULL;
            bool pass = e < tau;
            u64 m = __ballot(pass);
            if (m) {
                int bs = 0;
                if (lane == 0) bs = atomicAdd(&cnt, (int)__popcll(m));
                bs = __shfl(bs, 0);
                if (pass) {
                    int p = bs + (int)__popcll(m & ((1ULL << lane) - 1ULL));
                    if (p < 1024) s[p] = e;
                }
            }
        }
        __syncthreads();
        if (cnt > 512) {
            bitonic1024(s, t);
            if (t == 0) { cnt = 128; tauf = s[127]; }
            #pragma unroll
            for (int q = 0; q < 4; ++q) { int n2 = t + q * 256; if (n2 >= 128) s[n2] = ~0ULL; }
        }
        __syncthreads();
    }
    bitonic1024(s, t);
    if (t < RKEEP) refI[b * RKEEP + t] = (int)(unsigned)(s[t] & 0xffffffffULL);
}

// ---------- exact fp32 refine of RKEEP survivors -> top-96 + S ----------
__global__ __launch_bounds__(256) void refine(
    const float* __restrict__ kmat, const float* __restrict__ kiall,
    const float* __restrict__ knorm, const float* __restrict__ kinorm,
    const int* __restrict__ refI, int* __restrict__ Ifin, float* __restrict__ Sbuf)
{
    int b = blockIdx.x, t = threadIdx.x;
    int w = t >> 6, lane = t & 63;
    __shared__ float kk[256];
    __shared__ u64 s[512];
    kk[t] = kmat[b * D_MAIN + t];
    s[t] = ~0ULL; s[t + 256] = ~0ULL;
    __syncthreads();
    float kn = knorm[b];
    for (int sv = w; sv < RKEEP; sv += 4) {
        int n = refI[b * RKEEP + sv];
        float4 a = *(const float4*)&kk[lane * 4];
        float4 bb = ((const float4*)(kiall + (size_t)n * D_MAIN))[lane];
        float d = a.x * bb.x + a.y * bb.y + a.z * bb.z + a.w * bb.w;
        d = wsum(d);
        if (lane == 0) {
            float d2 = kn + kinorm[n] - 2.f * d;
            s[sv] = ((u64)fkey(d2) << 32) | (unsigned)n;
        }
    }
    __syncthreads();
    bitonic512(s, t);
    if (t < CTX) {
        u64 e = s[t];
        Ifin[b * CTX + t] = (int)(unsigned)(e & 0xffffffffULL);
        Sbuf[b * CTX + t] = finv((unsigned)(e >> 32));
    }
}

// ---------- gather diff (bf16) ----------
__global__ __launch_bounds__(64) void gather_diff_bf(
    const float* __restrict__ kmat, const float* __restrict__ kiall,
    const int* __restrict__ I, unsigned short* __restrict__ diffb)
{
    int bc = blockIdx.x;
    int b = bc / CTX;
    int t = threadIdx.x;
    int idx = I[bc];
    float4 kv = ((const float4*)(kmat + (size_t)b * D_MAIN))[t];
    float4 iv = ((const float4*)(kiall + (size_t)idx * D_MAIN))[t];
    ushort4 u;
    u.x = f2b(kv.x - iv.x); u.y = f2b(kv.y - iv.y);
    u.z = f2b(kv.z - iv.z); u.w = f2b(kv.w - iv.w);
    ((ushort4*)(diffb + (size_t)bc * D_MAIN))[t] = u;
}

// ---------- softmax over 96 ----------
__global__ __launch_bounds__(128) void softmax96(const float* __restrict__ S,
                                                 float* __restrict__ w)
{
    int b = blockIdx.x, t = threadIdx.x;
    __shared__ float rm[2], rs[2];
    float v = (t < CTX) ? S[b * CTX + t] : -__builtin_inff();
    float m = wmax(v);
    if ((t & 63) == 0) rm[t >> 6] = m;
    __syncthreads();
    m = fmaxf(rm[0], rm[1]);
    float e = (t < CTX) ? expf(v - m) : 0.f;
    float ss = wsum(e);
    if ((t & 63) == 0) rs[t >> 6] = ss;
    __syncthreads();
    float Z = rs[0] + rs[1];
    if (t < CTX) w[b * CTX + t] = e / Z;
}

// ---------- aggregation ----------
__global__ __launch_bounds__(256) void aggregate(
    const float* __restrict__ w, const int* __restrict__ I,
    const int* __restrict__ cand_y, const float* __restrict__ Yemb,
    const float* __restrict__ mlp, const float* __restrict__ x,
    float* __restrict__ x2)
{
    int b = blockIdx.x, t = threadIdx.x;
    __shared__ float ws[CTX];
    __shared__ int lab[CTX];
    if (t < CTX) {
        ws[t] = w[b * CTX + t];
        lab[t] = cand_y[I[b * CTX + t]];
    }
    __syncthreads();
    float acc = 0.f;
    for (int c = 0; c < CTX; ++c) {
        acc += ws[c] * (Yemb[lab[c] * D_MAIN + t] + mlp[((size_t)b * CTX + c) * D_MAIN + t]);
    }
    x2[b * D_MAIN + t] = x[b * D_MAIN + t] + acc;
}

// ---------- predictor block + head ----------
__global__ __launch_bounds__(256) void predictor_head(
    const float* __restrict__ x2,
    const float* __restrict__ lns, const float* __restrict__ lnb,
    const float* __restrict__ W1, const float* __restrict__ b1,
    const float* __restrict__ W2, const float* __restrict__ b2,
    const float* __restrict__ plns, const float* __restrict__ plnb,
    const float* __restrict__ PW, const float* __restrict__ Pb,
    float* __restrict__ out)
{
    int b = blockIdx.x, t = threadIdx.x;
    __shared__ float ln1[256], hdn[512], red[4];
    float xv = x2[b * D_MAIN + t];
    float s1 = blockSum256(xv, red);
    float s2 = blockSum256(xv * xv, red);
    float mean = s1 * (1.f / 256.f);
    float var = s2 * (1.f / 256.f) - mean * mean;
    float rstd = rsqrtf(var + 1e-5f);
    ln1[t] = (xv - mean) * rstd * lns[t] + lnb[t];
    __syncthreads();
    #pragma unroll
    for (int rep = 0; rep < 2; ++rep) {
        int j = t + rep * 256;
        float a = b1[j];
        for (int i = 0; i < 256; ++i) a += ln1[i] * W1[i * D_INT + j];
        hdn[j] = fmaxf(a, 0.f);
    }
    __syncthreads();
    float a3 = b2[t];
    for (int i = 0; i < 512; ++i) a3 += hdn[i] * W2[i * D_MAIN + t];
    float x3 = xv + a3;
    float s3 = blockSum256(x3, red);
    float s4 = blockSum256(x3 * x3, red);
    float m2 = s3 * (1.f / 256.f);
    float v2 = s4 * (1.f / 256.f) - m2 * m2;
    float r2 = rsqrtf(v2 + 1e-5f);
    float rv = fmaxf((x3 - m2) * r2 * plns[t] + plnb[t], 0.f);
    __syncthreads();
    ln1[t] = rv;
    __syncthreads();
    if (t < N_CLS) {
        float a = Pb[t];
        for (int i = 0; i < 256; ++i) a += ln1[i] * PW[i * N_CLS + t];
        out[b * N_CLS + t] = a;
    }
}

// ---------- host-side launch ----------
extern "C" void kernel_launch(void* const* d_in, const int* in_sizes, int n_in,
                              void* d_out, int out_size, void* d_ws, size_t ws_size,
                              hipStream_t stream)
{
    (void)in_sizes; (void)n_in; (void)out_size; (void)ws_size;
    const float* x_num   = (const float*)d_in[0];
    const float* cand    = (const float*)d_in[1];
    const int*   cand_y  = (const int*)d_in[2];
    const float* W_lin   = (const float*)d_in[4];
    const float* b_lin   = (const float*)d_in[5];
    const float* W_K     = (const float*)d_in[6];
    const float* b_K     = (const float*)d_in[7];
    const float* Y_emb   = (const float*)d_in[8];
    const float* T_W1    = (const float*)d_in[9];
    const float* T_b1    = (const float*)d_in[10];
    const float* T_W2    = (const float*)d_in[11];
    const float* bp_ln_s = (const float*)d_in[12];
    const float* bp_ln_b = (const float*)d_in[13];
    const float* bp_W1   = (const float*)d_in[14];
    const float* bp_b1   = (const float*)d_in[15];
    const float* bp_W2   = (const float*)d_in[16];
    const float* bp_b2   = (const float*)d_in[17];
    const float* P_ln_s  = (const float*)d_in[18];
    const float* P_ln_b  = (const float*)d_in[19];
    const float* P_W     = (const float*)d_in[20];
    const float* P_b     = (const float*)d_in[21];
    float* outp = (float*)d_out;

    char* ws = (char*)d_ws;
    float* kiall  = (float*)(ws + 0);
    unsigned short* hidden = (unsigned short*)(ws + 0);
    unsigned short* ki_bf = (unsigned short*)(ws + 102400000);
    unsigned short* diffb = (unsigned short*)(ws + 102400000);
    float* mlpbuf = (float*)(ws + 102400000);
    float* scores = (float*)(ws + 153600000);
    u64*   surv   = (u64*)(ws + 153600000);
    const size_t T = 204800000;
    float* xbuf   = (float*)(ws + T + 0);
    float* kbuf   = (float*)(ws + T + 1048576);
    float* x2buf  = (float*)(ws + T + 2097152);
    float* knorm  = (float*)(ws + T + 3145728);
    float* kinorm = (float*)(ws + T + 3149824);
    unsigned short* k_bf = (unsigned short*)(ws + T + 3551232);
    float* Wf     = (float*)(ws + T + 4075520);            // 128x256 f32
    unsigned short* WfH = (unsigned short*)(ws + T + 4206592);  // 256x128 bf16
    unsigned short* WfL = (unsigned short*)(ws + T + 4272128);
    float* bfused = (float*)(ws + T + 4337664);            // 256 f32
    unsigned short* W1t  = (unsigned short*)(ws + T + 4468736);
    unsigned short* W2t  = (unsigned short*)(ws + T + 4730880);
    float* Sbuf   = (float*)(ws + T + 4993024);
    float* wbuf   = (float*)(ws + T + 5386240);
    int*   refI   = (int*)(ws + T + 5779456);
    int*   Ifin   = (int*)(ws + T + 6303744);
    u64*   pilotbuf = (u64*)(ws + T + 6696960);
    unsigned* tau32 = (unsigned*)(ws + T + 7745536);
    int*   svcnt  = (int*)(ws + T + 7749632);

    // 1. batch encode (exact fp32, fused bf16 emit)
    encode_batch<<<B_ROWS, 256, 0, stream>>>(x_num, W_lin, b_lin, W_K, b_K,
                                             xbuf, kbuf, knorm, k_bf);
    // 2. fused encoder weights (fp32): Wf = Wl@Wk, bf = bl@Wk + bk; split to bf16
    fuse_weights<<<129, 256, 0, stream>>>(W_lin, W_K, b_lin, b_K, Wf, bfused);
    cvt_split_transpose<<<128, 256, 0, stream>>>(Wf, WfH, WfL, N_FEAT, D_MAIN);
    cvt_transpose<<<512, 256, 0, stream>>>(T_W1, W1t, D_MAIN, D_INT);
    cvt_transpose<<<512, 256, 0, stream>>>(T_W2, W2t, D_INT, D_MAIN);
    // 3. candidate keys via ONE fused split-bf16 GEMM (fp32-accurate), K=128
    gemm_split3<true><<<dim3(782, 4), 256, 0, stream>>>(
        cand, WfH, WfL, bfused, kiall, ki_bf, N_CAND, D_MAIN, N_FEAT);
    // 4. candidate norms
    rownorms<<<25000, 256, 0, stream>>>(kiall, kinorm, N_CAND);
    // 5. pilot: screen first PCHN candidates, exact top-128 + tau
    screen_gemm<1><<<dim3(8, PCHN / 64), 256, 0, stream>>>(
        k_bf, ki_bf, scores, PCHN, 0, kinorm, nullptr, nullptr, nullptr);
    pilot_select<<<B_ROWS, 256, 0, stream>>>(scores, pilotbuf, tau32);
    init_surv<<<B_ROWS, 128, 0, stream>>>(pilotbuf, surv, svcnt);
    // 6. fused screen+filter over remaining candidates
    screen_gemm<2><<<dim3(8, (N2 + 63) / 64), 256, 0, stream>>>(
        k_bf, ki_bf + (size_t)PCHN * D_MAIN, nullptr, N2, PCHN,
        kinorm + PCHN, tau32, svcnt, surv);
    // 7. final exact top-128 of survivors -> refI
    final_select<<<B_ROWS, 256, 0, stream>>>(surv, svcnt, refI);
    // 8. exact fp32 refine -> top-96 + S
    refine<<<B_ROWS, 256, 0, stream>>>(kbuf, kiall, knorm, kinorm, refI, Ifin, Sbuf);
    // 9. softmax weights
    softmax96<<<B_ROWS, 128, 0, stream>>>(Sbuf, wbuf);
    // 10. gather diff (bf16)
    gather_diff_bf<<<B_ROWS * CTX, 64, 0, stream>>>(kbuf, kiall, Ifin, diffb);
    // 11. T-MLP on MFMA (128x64 tiles, dbuf)
    gemm_bf16<true, true><<<dim3(768, 8), 256, 0, stream>>>(
        diffb, W1t, T_b1, hidden, B_ROWS * CTX, D_INT, D_MAIN);
    gemm_bf16<false, false><<<dim3(768, 4), 256, 0, stream>>>(
        hidden, W2t, nullptr, mlpbuf, B_ROWS * CTX, D_MAIN, D_INT);
    // 12. aggregate
    aggregate<<<B_ROWS, 256, 0, stream>>>(wbuf, Ifin, cand_y, Y_emb, mlpbuf,
                                          xbuf, x2buf);
    // 13. predictor + head
    predictor_head<<<B_ROWS, 256, 0, stream>>>(x2buf, bp_ln_s, bp_ln_b,
                                               bp_W1, bp_b1, bp_W2, bp_b2,
                                               P_ln_s, P_ln_b, P_W, P_b, outp);
}

// Round 17
// 794.642 us; speedup vs baseline: 1.1701x; 1.0038x over previous
//
#include <hip/hip_runtime.h>
#include <hip/hip_bf16.h>

#define B_ROWS   1024
#define N_FEAT   128
#define D_MAIN   256
#define D_INT    512
#define N_CAND   100000
#define CTX      96
#define N_CLS    10
#define PCHN     8192    // pilot chunk size (measured optimum)
#define N2       91808   // remaining candidates (fused filter path)
#define RKEEP    128     // refine set size
#define SCAP     6144    // survivor cap per row
#define SVSTRIDE 16      // svcnt padded to one counter per 64B line

typedef __attribute__((ext_vector_type(8))) short bf16x8;
typedef __attribute__((ext_vector_type(4))) float f32x4;
typedef unsigned long long u64;

// ---------- helpers ----------
__device__ __forceinline__ float wsum(float v) {
    #pragma unroll
    for (int o = 32; o > 0; o >>= 1) v += __shfl_down(v, o);
    return v;
}
__device__ __forceinline__ float wmax(float v) {
    #pragma unroll
    for (int o = 32; o > 0; o >>= 1) v = fmaxf(v, __shfl_down(v, o));
    return v;
}
__device__ __forceinline__ float blockSum256(float v, float* red) {
    int t = threadIdx.x;
    float s = wsum(v);
    if ((t & 63) == 0) red[t >> 6] = s;
    __syncthreads();
    s = red[0] + red[1] + red[2] + red[3];
    __syncthreads();
    return s;
}
__device__ __forceinline__ float b2f(unsigned short u) {
    return __uint_as_float(((unsigned)u) << 16);
}
__device__ __forceinline__ unsigned short f2b(float f) {
    unsigned x = __float_as_uint(f);
    return (unsigned short)((x + 0x7fff + ((x >> 16) & 1)) >> 16);
}
__device__ __forceinline__ unsigned fkey(float f) {
    unsigned u = __float_as_uint(f);
    return u ^ ((((int)u >> 31)) | 0x80000000u);
}
__device__ __forceinline__ float finv(unsigned k) {
    unsigned u = (k & 0x80000000u) ? (k ^ 0x80000000u) : ~k;
    return __uint_as_float(u);
}
#define SPLIT1(x, hv, lv) { unsigned short _h = f2b(x); hv = (short)_h; lv = (short)f2b((x) - b2f(_h)); }

// ---------- K1: batch encode (also emits bf16 copy of k) ----------
__global__ __launch_bounds__(256) void encode_batch(
    const float* __restrict__ xn, const float* __restrict__ Wl, const float* __restrict__ bl,
    const float* __restrict__ Wk, const float* __restrict__ bk,
    float* __restrict__ xout, float* __restrict__ kout, float* __restrict__ knorm,
    unsigned short* __restrict__ kbf)
{
    int b = blockIdx.x, t = threadIdx.x;
    __shared__ float si[128], sx[256], red[4];
    if (t < 128) si[t] = xn[b * N_FEAT + t];
    __syncthreads();
    float a = bl[t];
    for (int i = 0; i < 128; ++i) a += si[i] * Wl[i * D_MAIN + t];
    xout[b * D_MAIN + t] = a;
    sx[t] = a;
    __syncthreads();
    float a2 = bk[t];
    for (int i = 0; i < 256; ++i) a2 += sx[i] * Wk[i * D_MAIN + t];
    kout[b * D_MAIN + t] = a2;
    kbf[b * D_MAIN + t] = f2b(a2);
    float s = blockSum256(a2 * a2, red);
    if (t == 0) knorm[b] = s;
}

// ---------- fused encoder weights, direct split+transpose emit ----------
// Wf = Wl@Wk (fp32 in registers) -> WfH/WfL [D_MAIN x N_FEAT] bf16 hi/lo
// block 128: bfused = bl@Wk + bk
__global__ __launch_bounds__(256) void fuse_weights_split(
    const float* __restrict__ Wl, const float* __restrict__ Wk,
    const float* __restrict__ bl, const float* __restrict__ bk,
    unsigned short* __restrict__ WfH, unsigned short* __restrict__ WfL,
    float* __restrict__ bf)
{
    int i = blockIdx.x, t = threadIdx.x;
    __shared__ float row[256];
    if (i < 128) {
        row[t] = Wl[i * D_MAIN + t];
        __syncthreads();
        float a = 0.f;
        for (int k = 0; k < 256; ++k) a += row[k] * Wk[k * D_MAIN + t];
        unsigned short h = f2b(a);
        WfH[(size_t)t * N_FEAT + i] = h;
        WfL[(size_t)t * N_FEAT + i] = f2b(a - b2f(h));
    } else {
        row[t] = bl[t];
        __syncthreads();
        float a = bk[t];
        for (int k = 0; k < 256; ++k) a += row[k] * Wk[k * D_MAIN + t];
        bf[t] = a;
    }
}

// ---------- split-bf16 fp32-accurate GEMM, 128x64 tile, acc[4][2] ----------
template<bool WRITE_BF16>
__global__ __launch_bounds__(256) void gemm_split3(
    const float* __restrict__ A,
    const unsigned short* __restrict__ Bh,
    const unsigned short* __restrict__ Bl,
    const float* __restrict__ bias,
    float* __restrict__ Cf,
    unsigned short* __restrict__ Cbf,
    int M, int N, int K)
{
    __shared__ __align__(16) short Ash[4096], Asl[4096];   // 128 x 32
    __shared__ __align__(16) short Bsh[2048], Bsl[2048];   // 64 x 32
    const int t = threadIdx.x;
    const int bm = blockIdx.x * 128, bn = blockIdx.y * 64;
    const int wave = t >> 6, lane = t & 63;
    const int wm = (wave >> 1) * 64, wn = (wave & 1) * 32;
    const int lr = lane & 15, lkg = lane >> 4;
    f32x4 acc[4][2] = {};
    const int row0 = t >> 2, kg0 = t & 3;     // row0 in 0..63
    const int row1 = row0 + 64;
    const int p0 = ((kg0 + (row0 >> 2)) & 3) ^ (row0 & 3);
    const int p1 = ((kg0 + (row1 >> 2)) & 3) ^ (row1 & 3);
    const int gm0 = bm + row0, gm1 = bm + row1;
    const int nB = bn + row0;

    float4 u00, u01, u10, u11;
    bf16x8 bh0, bl0;
    auto prefetch = [&](int kq) {
        float4 z4 = make_float4(0.f, 0.f, 0.f, 0.f); bf16x8 z = {};
        u00 = z4; u01 = z4; u10 = z4; u11 = z4;
        bh0 = z; bl0 = z;
        if (gm0 < M) {
            const float* ap = A + (size_t)gm0 * K + kq + kg0 * 8;
            u00 = *(const float4*)ap; u01 = *(const float4*)(ap + 4);
        }
        if (gm1 < M) {
            const float* ap = A + (size_t)gm1 * K + kq + kg0 * 8;
            u10 = *(const float4*)ap; u11 = *(const float4*)(ap + 4);
        }
        if (nB < N) {
            bh0 = *(const bf16x8*)(Bh + (size_t)nB * K + kq + kg0 * 8);
            bl0 = *(const bf16x8*)(Bl + (size_t)nB * K + kq + kg0 * 8);
        }
    };
    prefetch(0);

    for (int k0 = 0; k0 < K; k0 += 32) {
        bf16x8 a0h, a0l, a1h, a1l;
        SPLIT1(u00.x, a0h[0], a0l[0]); SPLIT1(u00.y, a0h[1], a0l[1]);
        SPLIT1(u00.z, a0h[2], a0l[2]); SPLIT1(u00.w, a0h[3], a0l[3]);
        SPLIT1(u01.x, a0h[4], a0l[4]); SPLIT1(u01.y, a0h[5], a0l[5]);
        SPLIT1(u01.z, a0h[6], a0l[6]); SPLIT1(u01.w, a0h[7], a0l[7]);
        SPLIT1(u10.x, a1h[0], a1l[0]); SPLIT1(u10.y, a1h[1], a1l[1]);
        SPLIT1(u10.z, a1h[2], a1l[2]); SPLIT1(u10.w, a1h[3], a1l[3]);
        SPLIT1(u11.x, a1h[4], a1l[4]); SPLIT1(u11.y, a1h[5], a1l[5]);
        SPLIT1(u11.z, a1h[6], a1l[6]); SPLIT1(u11.w, a1h[7], a1l[7]);
        __syncthreads();
        *(bf16x8*)&Ash[(row0 * 4 + p0) * 8] = a0h;
        *(bf16x8*)&Asl[(row0 * 4 + p0) * 8] = a0l;
        *(bf16x8*)&Ash[(row1 * 4 + p1) * 8] = a1h;
        *(bf16x8*)&Asl[(row1 * 4 + p1) * 8] = a1l;
        *(bf16x8*)&Bsh[(row0 * 4 + p0) * 8] = bh0;
        *(bf16x8*)&Bsl[(row0 * 4 + p0) * 8] = bl0;
        if (k0 + 32 < K) prefetch(k0 + 32);
        __syncthreads();
        bf16x8 bfh[2], bfl[2];
        #pragma unroll
        for (int n = 0; n < 2; ++n) {
            int r = wn + n * 16 + lr;
            int p = ((lkg + (r >> 2)) & 3) ^ (r & 3);
            bfh[n] = *(const bf16x8*)&Bsh[(r * 4 + p) * 8];
            bfl[n] = *(const bf16x8*)&Bsl[(r * 4 + p) * 8];
        }
        #pragma unroll
        for (int m = 0; m < 4; ++m) {
            int r = wm + m * 16 + lr;
            int p = ((lkg + (r >> 2)) & 3) ^ (r & 3);
            bf16x8 ah = *(const bf16x8*)&Ash[(r * 4 + p) * 8];
            bf16x8 al = *(const bf16x8*)&Asl[(r * 4 + p) * 8];
            #pragma unroll
            for (int n = 0; n < 2; ++n) {
                acc[m][n] = __builtin_amdgcn_mfma_f32_16x16x32_bf16(al, bfh[n], acc[m][n], 0, 0, 0);
                acc[m][n] = __builtin_amdgcn_mfma_f32_16x16x32_bf16(ah, bfl[n], acc[m][n], 0, 0, 0);
                acc[m][n] = __builtin_amdgcn_mfma_f32_16x16x32_bf16(ah, bfh[n], acc[m][n], 0, 0, 0);
            }
        }
    }
    #pragma unroll
    for (int m = 0; m < 4; ++m) {
        #pragma unroll
        for (int n = 0; n < 2; ++n) {
            f32x4 a = acc[m][n];
            int gcol = bn + wn + n * 16 + lr;
            if (gcol >= N) continue;
            float bv = bias[gcol];
            #pragma unroll
            for (int r = 0; r < 4; ++r) {
                int grow = bm + wm + m * 16 + lkg * 4 + r;
                if (grow >= M) continue;
                float v = a[r] + bv;
                Cf[(size_t)grow * N + gcol] = v;
                if (WRITE_BF16) Cbf[(size_t)grow * N + gcol] = f2b(v);
            }
        }
    }
}

// ---------- T-MLP bf16 GEMM: 128x64 tile, acc[4][2], dbuf LDS (1 barrier/K-step) ----------
template<bool RELU, bool OUT_BF16>
__global__ __launch_bounds__(256) void gemm_bf16(
    const unsigned short* __restrict__ A,
    const unsigned short* __restrict__ Bt,
    const float* __restrict__ bias,
    void* __restrict__ C, int M, int N, int K)
{
    __shared__ __align__(16) short As[2][4096];
    __shared__ __align__(16) short Bs[2][2048];
    const int t = threadIdx.x;
    const int bm = blockIdx.x * 128, bn = blockIdx.y * 64;
    const int wave = t >> 6, lane = t & 63;
    const int wm = (wave >> 1) * 64, wn = (wave & 1) * 32;
    const int lr = lane & 15, lkg = lane >> 4;
    f32x4 acc[4][2] = {};
    const int row0 = t >> 2, kg0 = t & 3;
    const int row1 = row0 + 64;
    const int p0 = ((kg0 + (row0 >> 2)) & 3) ^ (row0 & 3);
    const int p1 = ((kg0 + (row1 >> 2)) & 3) ^ (row1 & 3);
    const int gm0 = bm + row0, gm1 = bm + row1;
    const int nB = bn + row0;

    bf16x8 a0, a1, b0;
    auto prefetch = [&](int kq) {
        bf16x8 z = {};
        a0 = z; a1 = z; b0 = z;
        if (gm0 < M) a0 = *(const bf16x8*)(A + (size_t)gm0 * K + kq + kg0 * 8);
        if (gm1 < M) a1 = *(const bf16x8*)(A + (size_t)gm1 * K + kq + kg0 * 8);
        if (nB < N) b0 = *(const bf16x8*)(Bt + (size_t)nB * K + kq + kg0 * 8);
    };
    prefetch(0);
    *(bf16x8*)&As[0][(row0 * 4 + p0) * 8] = a0;
    *(bf16x8*)&As[0][(row1 * 4 + p1) * 8] = a1;
    *(bf16x8*)&Bs[0][(row0 * 4 + p0) * 8] = b0;
    if (32 < K) prefetch(32);
    __syncthreads();

    for (int k0 = 0; k0 < K; k0 += 32) {
        const int cur = (k0 >> 5) & 1;
        if (k0 + 32 < K) {
            const int nxt = cur ^ 1;
            *(bf16x8*)&As[nxt][(row0 * 4 + p0) * 8] = a0;
            *(bf16x8*)&As[nxt][(row1 * 4 + p1) * 8] = a1;
            *(bf16x8*)&Bs[nxt][(row0 * 4 + p0) * 8] = b0;
            if (k0 + 64 < K) prefetch(k0 + 64);
        }
        bf16x8 bfr[2];
        #pragma unroll
        for (int n = 0; n < 2; ++n) {
            int r = wn + n * 16 + lr;
            int p = ((lkg + (r >> 2)) & 3) ^ (r & 3);
            bfr[n] = *(const bf16x8*)&Bs[cur][(r * 4 + p) * 8];
        }
        #pragma unroll
        for (int m = 0; m < 4; ++m) {
            int r = wm + m * 16 + lr;
            int p = ((lkg + (r >> 2)) & 3) ^ (r & 3);
            bf16x8 af = *(const bf16x8*)&As[cur][(r * 4 + p) * 8];
            #pragma unroll
            for (int n = 0; n < 2; ++n)
                acc[m][n] = __builtin_amdgcn_mfma_f32_16x16x32_bf16(
                    af, bfr[n], acc[m][n], 0, 0, 0);
        }
        __syncthreads();
    }
    #pragma unroll
    for (int m = 0; m < 4; ++m) {
        #pragma unroll
        for (int n = 0; n < 2; ++n) {
            f32x4 a = acc[m][n];
            int gcol = bn + wn + n * 16 + lr;
            if (gcol >= N) continue;
            float bv = bias ? bias[gcol] : 0.f;
            #pragma unroll
            for (int r = 0; r < 4; ++r) {
                int grow = bm + wm + m * 16 + lkg * 4 + r;
                if (grow >= M) continue;
                float v = a[r] + bv;
                if (RELU) v = fmaxf(v, 0.f);
                if (OUT_BF16)
                    ((unsigned short*)C)[(size_t)grow * N + gcol] = f2b(v);
                else
                    ((float*)C)[(size_t)grow * N + gcol] = v;
            }
        }
    }
}

// ---------- screen GEMM: 128x64 tile, acc[4][2], dbuf LDS (1 barrier/K-step) ----------
// MODE 1: write scores.  MODE 2: tau-filtered survivor append.
template<int MODE>
__global__ __launch_bounds__(256) void screen_gemm(
    const unsigned short* __restrict__ A,   // k_bf [1024,256]
    const unsigned short* __restrict__ Bt,  // ki_bf span [N,256]
    float* __restrict__ scores,
    int N, int n0,
    const float* __restrict__ knrm,
    const unsigned* __restrict__ tau32, int* __restrict__ svcnt,
    u64* __restrict__ surv)
{
    __shared__ __align__(16) short As[2][4096];
    __shared__ __align__(16) short Bs[2][2048];
    const int t = threadIdx.x;
    const int bm = blockIdx.x * 128, bn = blockIdx.y * 64;
    const int wave = t >> 6, lane = t & 63;
    const int wm = (wave >> 1) * 64, wn = (wave & 1) * 32;
    const int lr = lane & 15, lkg = lane >> 4;
    f32x4 acc[4][2] = {};
    const int row0 = t >> 2, kg0 = t & 3;
    const int row1 = row0 + 64;
    const int p0 = ((kg0 + (row0 >> 2)) & 3) ^ (row0 & 3);
    const int p1 = ((kg0 + (row1 >> 2)) & 3) ^ (row1 & 3);
    const int gm0 = bm + row0, gm1 = bm + row1;   // < 1024 always
    const int nB = bn + row0;

    bf16x8 a0, a1, b0;
    auto prefetch = [&](int kq) {
        bf16x8 z = {};
        b0 = z;
        a0 = *(const bf16x8*)(A + (size_t)gm0 * D_MAIN + kq + kg0 * 8);
        a1 = *(const bf16x8*)(A + (size_t)gm1 * D_MAIN + kq + kg0 * 8);
        if (nB < N) b0 = *(const bf16x8*)(Bt + (size_t)nB * D_MAIN + kq + kg0 * 8);
    };
    prefetch(0);
    *(bf16x8*)&As[0][(row0 * 4 + p0) * 8] = a0;
    *(bf16x8*)&As[0][(row1 * 4 + p1) * 8] = a1;
    *(bf16x8*)&Bs[0][(row0 * 4 + p0) * 8] = b0;
    prefetch(32);
    __syncthreads();

    for (int k0 = 0; k0 < D_MAIN; k0 += 32) {
        const int cur = (k0 >> 5) & 1;
        if (k0 + 32 < D_MAIN) {
            const int nxt = cur ^ 1;
            *(bf16x8*)&As[nxt][(row0 * 4 + p0) * 8] = a0;
            *(bf16x8*)&As[nxt][(row1 * 4 + p1) * 8] = a1;
            *(bf16x8*)&Bs[nxt][(row0 * 4 + p0) * 8] = b0;
            if (k0 + 64 < D_MAIN) prefetch(k0 + 64);
        }
        bf16x8 bfr[2];
        #pragma unroll
        for (int n = 0; n < 2; ++n) {
            int r = wn + n * 16 + lr;
            int p = ((lkg + (r >> 2)) & 3) ^ (r & 3);
            bfr[n] = *(const bf16x8*)&Bs[cur][(r * 4 + p) * 8];
        }
        #pragma unroll
        for (int m = 0; m < 4; ++m) {
            int r = wm + m * 16 + lr;
            int p = ((lkg + (r >> 2)) & 3) ^ (r & 3);
            bf16x8 af = *(const bf16x8*)&As[cur][(r * 4 + p) * 8];
            #pragma unroll
            for (int n = 0; n < 2; ++n)
                acc[m][n] = __builtin_amdgcn_mfma_f32_16x16x32_bf16(
                    af, bfr[n], acc[m][n], 0, 0, 0);
        }
        __syncthreads();
    }

    float knv[2];
    #pragma unroll
    for (int n = 0; n < 2; ++n) {
        int gcol = bn + wn + n * 16 + lr;
        knv[n] = (gcol < N) ? knrm[gcol] : 0.f;
    }
    if (MODE == 1) {
        #pragma unroll
        for (int m = 0; m < 4; ++m) {
            #pragma unroll
            for (int n = 0; n < 2; ++n) {
                int gcol = bn + wn + n * 16 + lr;
                if (gcol >= N) continue;
                #pragma unroll
                for (int r = 0; r < 4; ++r) {
                    int grow = bm + wm + m * 16 + lkg * 4 + r;
                    scores[(size_t)grow * PCHN + gcol] = knv[n] - 2.0f * acc[m][n][r];
                }
            }
        }
    } else {
        unsigned taur[16];
        #pragma unroll
        for (int m = 0; m < 4; ++m)
            #pragma unroll
            for (int r = 0; r < 4; ++r)
                taur[m * 4 + r] = tau32[bm + wm + m * 16 + lkg * 4 + r];
        #pragma unroll
        for (int m = 0; m < 4; ++m) {
            #pragma unroll
            for (int r = 0; r < 4; ++r) {
                int grow = bm + wm + m * 16 + lkg * 4 + r;
                #pragma unroll
                for (int n = 0; n < 2; ++n) {
                    int gcol = bn + wn + n * 16 + lr;
                    bool pass = false;
                    unsigned key = 0;
                    if (gcol < N) {
                        key = fkey(knv[n] - 2.0f * acc[m][n][r]);
                        pass = key <= taur[m * 4 + r];
                    }
                    u64 bal = __ballot(pass);
                    unsigned g16 = (unsigned)((bal >> (lkg * 16)) & 0xFFFFu);
                    if (g16) {
                        int cntp = __popc(g16);
                        int first = __ffs(g16) - 1;
                        int base = 0;
                        if (lr == first) base = atomicAdd(&svcnt[grow * SVSTRIDE], cntp);
                        base = __shfl(base, lkg * 16 + first);
                        if (pass) {
                            int p = base + __popc(g16 & ((1u << lr) - 1u));
                            if (p < SCAP)
                                surv[(size_t)grow * SCAP + p] =
                                    ((u64)key << 32) | (unsigned)(n0 + gcol);
                        }
                    }
                }
            }
        }
    }
}

// ---------- single transpose pass for both T-MLP weights ----------
__global__ __launch_bounds__(256) void cvt_transpose2(
    const float* __restrict__ W1, unsigned short* __restrict__ W1t,
    const float* __restrict__ W2, unsigned short* __restrict__ W2t)
{
    int idx = blockIdx.x * 256 + threadIdx.x;
    if (idx < D_MAIN * D_INT) {
        int k = idx / D_INT, n = idx % D_INT;
        W1t[(size_t)n * D_MAIN + k] = f2b(W1[idx]);
    } else {
        idx -= D_MAIN * D_INT;
        int k = idx / D_MAIN, n = idx % D_MAIN;
        W2t[(size_t)n * D_INT + k] = f2b(W2[idx]);
    }
}

// ---------- row norms ----------
__global__ __launch_bounds__(256) void rownorms(const float* __restrict__ ki,
                                                float* __restrict__ out, int M)
{
    int n = blockIdx.x * 4 + (threadIdx.x >> 6);
    int lane = threadIdx.x & 63;
    if (n >= M) return;
    float4 v = *(const float4*)(ki + (size_t)n * D_MAIN + lane * 4);
    float s = v.x * v.x + v.y * v.y + v.z * v.z + v.w * v.w;
    s = wsum(s);
    if (lane == 0) out[n] = s;
}

// ---------- bitonic sorts ----------
__device__ void bitonic512(u64* s, int t)
{
    for (int k = 2; k <= 512; k <<= 1) {
        for (int j = k >> 1; j > 0; j >>= 1) {
            __syncthreads();
            #pragma unroll
            for (int q = 0; q < 2; ++q) {
                int l = t + q * 256;
                int p = l ^ j;
                if (p > l) {
                    u64 a = s[l], bb = s[p];
                    bool up = ((l & k) == 0);
                    if ((a > bb) == up) { s[l] = bb; s[p] = a; }
                }
            }
        }
    }
    __syncthreads();
}
__device__ void bitonic1024(u64* s, int t)
{
    for (int k = 2; k <= 1024; k <<= 1) {
        for (int j = k >> 1; j > 0; j >>= 1) {
            __syncthreads();
            #pragma unroll
            for (int q = 0; q < 4; ++q) {
                int l = t + q * 256;
                int p = l ^ j;
                if (p > l) {
                    u64 a = s[l], bb = s[p];
                    bool up = ((l & k) == 0);
                    if ((a > bb) == up) { s[l] = bb; s[p] = a; }
                }
            }
        }
    }
    __syncthreads();
}

// ---------- pilot: exact top-128 of pilot scores -> surv/svcnt/tau directly ----------
__global__ __launch_bounds__(256) void pilot_select(
    const float* __restrict__ scores, u64* __restrict__ surv,
    int* __restrict__ svcnt, unsigned* __restrict__ tau32)
{
    int b = blockIdx.x, t = threadIdx.x;
    int lane = t & 63;
    __shared__ u64 s[1024];
    __shared__ int cnt;
    __shared__ u64 tauf;
    const float* row = scores + (size_t)b * PCHN;
    #pragma unroll
    for (int q = 0; q < 4; ++q) {
        int n = t + q * 256;
        s[n] = ((u64)fkey(row[n]) << 32) | (unsigned)n;
    }
    __syncthreads();
    bitonic1024(s, t);
    if (t == 0) { cnt = 128; tauf = s[127]; }
    #pragma unroll
    for (int q = 0; q < 4; ++q) { int n = t + q * 256; if (n >= 128) s[n] = ~0ULL; }
    __syncthreads();
    for (int base = 1024; base < PCHN; base += 1024) {
        u64 tau = tauf;
        int n = base + t * 4;
        float4 v = *(const float4*)(row + n);
        #pragma unroll
        for (int j = 0; j < 4; ++j) {
            float x = (&v.x)[j];
            u64 e = ((u64)fkey(x) << 32) | (unsigned)(n + j);
            bool pass = e < tau;
            u64 m = __ballot(pass);
            if (m) {
                int bs = 0;
                if (lane == 0) bs = atomicAdd(&cnt, (int)__popcll(m));
                bs = __shfl(bs, 0);
                if (pass) {
                    int p = bs + (int)__popcll(m & ((1ULL << lane) - 1ULL));
                    if (p < 1024) s[p] = e;
                }
            }
        }
        __syncthreads();
        if (cnt > 512) {
            bitonic1024(s, t);
            if (t == 0) { cnt = 128; tauf = s[127]; }
            #pragma unroll
            for (int q = 0; q < 4; ++q) { int n2 = t + q * 256; if (n2 >= 128) s[n2] = ~0ULL; }
        }
        __syncthreads();
    }
    bitonic1024(s, t);
    if (t < 128) surv[(size_t)b * SCAP + t] = s[t];
    if (t == 0) {
        tau32[b] = (unsigned)(s[127] >> 32);
        svcnt[b * SVSTRIDE] = 128;
    }
}

// ---------- final: exact top-128 of survivor set -> refI ----------
__global__ __launch_bounds__(256) void final_select(
    const u64* __restrict__ surv, const int* __restrict__ svcnt,
    int* __restrict__ refI)
{
    int b = blockIdx.x, t = threadIdx.x;
    int lane = t & 63;
    __shared__ u64 s[1024];
    __shared__ int cnt;
    __shared__ u64 tauf;
    int total = svcnt[b * SVSTRIDE]; if (total > SCAP) total = SCAP;
    const u64* rowp = surv + (size_t)b * SCAP;
    #pragma unroll
    for (int q = 0; q < 4; ++q) {
        int n = t + q * 256;
        s[n] = (n < total) ? rowp[n] : ~0ULL;
    }
    __syncthreads();
    bitonic1024(s, t);
    if (t == 0) { cnt = 128; tauf = s[127]; }
    #pragma unroll
    for (int q = 0; q < 4; ++q) { int n = t + q * 256; if (n >= 128) s[n] = ~0ULL; }
    __syncthreads();
    for (int base = 1024; base < total; base += 1024) {
        u64 tau = tauf;
        int n = base + t * 4;
        #pragma unroll
        for (int j = 0; j < 4; ++j) {
            u64 e = (n + j < total) ? rowp[n + j] : ~0ULL;
            bool pass = e < tau;
            u64 m = __ballot(pass);
            if (m) {
                int bs = 0;
                if (lane == 0) bs = atomicAdd(&cnt, (int)__popcll(m));
                bs = __shfl(bs, 0);
                if (pass) {
                    int p = bs + (int)__popcll(m & ((1ULL << lane) - 1ULL));
                    if (p < 1024) s[p] = e;
                }
            }
        }
        __syncthreads();
        if (cnt > 512) {
            bitonic1024(s, t);
            if (t == 0) { cnt = 128; tauf = s[127]; }
            #pragma unroll
            for (int q = 0; q < 4; ++q) { int n2 = t + q * 256; if (n2 >= 128) s[n2] = ~0ULL; }
        }
        __syncthreads();
    }
    bitonic1024(s, t);
    if (t < RKEEP) refI[b * RKEEP + t] = (int)(unsigned)(s[t] & 0xffffffffULL);
}

// ---------- exact fp32 refine of RKEEP survivors -> top-96 + S ----------
__global__ __launch_bounds__(256) void refine(
    const float* __restrict__ kmat, const float* __restrict__ kiall,
    const float* __restrict__ knorm, const float* __restrict__ kinorm,
    const int* __restrict__ refI, int* __restrict__ Ifin, float* __restrict__ Sbuf)
{
    int b = blockIdx.x, t = threadIdx.x;
    int w = t >> 6, lane = t & 63;
    __shared__ float kk[256];
    __shared__ u64 s[512];
    kk[t] = kmat[b * D_MAIN + t];
    s[t] = ~0ULL; s[t + 256] = ~0ULL;
    __syncthreads();
    float kn = knorm[b];
    for (int sv = w; sv < RKEEP; sv += 4) {
        int n = refI[b * RKEEP + sv];
        float4 a = *(const float4*)&kk[lane * 4];
        float4 bb = ((const float4*)(kiall + (size_t)n * D_MAIN))[lane];
        float d = a.x * bb.x + a.y * bb.y + a.z * bb.z + a.w * bb.w;
        d = wsum(d);
        if (lane == 0) {
            float d2 = kn + kinorm[n] - 2.f * d;
            s[sv] = ((u64)fkey(d2) << 32) | (unsigned)n;
        }
    }
    __syncthreads();
    bitonic512(s, t);
    if (t < CTX) {
        u64 e = s[t];
        Ifin[b * CTX + t] = (int)(unsigned)(e & 0xffffffffULL);
        Sbuf[b * CTX + t] = finv((unsigned)(e >> 32));
    }
}

// ---------- gather diff (bf16) ----------
__global__ __launch_bounds__(64) void gather_diff_bf(
    const float* __restrict__ kmat, const float* __restrict__ kiall,
    const int* __restrict__ I, unsigned short* __restrict__ diffb)
{
    int bc = blockIdx.x;
    int b = bc / CTX;
    int t = threadIdx.x;
    int idx = I[bc];
    float4 kv = ((const float4*)(kmat + (size_t)b * D_MAIN))[t];
    float4 iv = ((const float4*)(kiall + (size_t)idx * D_MAIN))[t];
    ushort4 u;
    u.x = f2b(kv.x - iv.x); u.y = f2b(kv.y - iv.y);
    u.z = f2b(kv.z - iv.z); u.w = f2b(kv.w - iv.w);
    ((ushort4*)(diffb + (size_t)bc * D_MAIN))[t] = u;
}

// ---------- softmax over 96 ----------
__global__ __launch_bounds__(128) void softmax96(const float* __restrict__ S,
                                                 float* __restrict__ w)
{
    int b = blockIdx.x, t = threadIdx.x;
    __shared__ float rm[2], rs[2];
    float v = (t < CTX) ? S[b * CTX + t] : -__builtin_inff();
    float m = wmax(v);
    if ((t & 63) == 0) rm[t >> 6] = m;
    __syncthreads();
    m = fmaxf(rm[0], rm[1]);
    float e = (t < CTX) ? expf(v - m) : 0.f;
    float ss = wsum(e);
    if ((t & 63) == 0) rs[t >> 6] = ss;
    __syncthreads();
    float Z = rs[0] + rs[1];
    if (t < CTX) w[b * CTX + t] = e / Z;
}

// ---------- aggregation ----------
__global__ __launch_bounds__(256) void aggregate(
    const float* __restrict__ w, const int* __restrict__ I,
    const int* __restrict__ cand_y, const float* __restrict__ Yemb,
    const float* __restrict__ mlp, const float* __restrict__ x,
    float* __restrict__ x2)
{
    int b = blockIdx.x, t = threadIdx.x;
    __shared__ float ws[CTX];
    __shared__ int lab[CTX];
    if (t < CTX) {
        ws[t] = w[b * CTX + t];
        lab[t] = cand_y[I[b * CTX + t]];
    }
    __syncthreads();
    float acc = 0.f;
    for (int c = 0; c < CTX; ++c) {
        acc += ws[c] * (Yemb[lab[c] * D_MAIN + t] + mlp[((size_t)b * CTX + c) * D_MAIN + t]);
    }
    x2[b * D_MAIN + t] = x[b * D_MAIN + t] + acc;
}

// ---------- predictor block + head ----------
__global__ __launch_bounds__(256) void predictor_head(
    const float* __restrict__ x2,
    const float* __restrict__ lns, const float* __restrict__ lnb,
    const float* __restrict__ W1, const float* __restrict__ b1,
    const float* __restrict__ W2, const float* __restrict__ b2,
    const float* __restrict__ plns, const float* __restrict__ plnb,
    const float* __restrict__ PW, const float* __restrict__ Pb,
    float* __restrict__ out)
{
    int b = blockIdx.x, t = threadIdx.x;
    __shared__ float ln1[256], hdn[512], red[4];
    float xv = x2[b * D_MAIN + t];
    float s1 = blockSum256(xv, red);
    float s2 = blockSum256(xv * xv, red);
    float mean = s1 * (1.f / 256.f);
    float var = s2 * (1.f / 256.f) - mean * mean;
    float rstd = rsqrtf(var + 1e-5f);
    ln1[t] = (xv - mean) * rstd * lns[t] + lnb[t];
    __syncthreads();
    #pragma unroll
    for (int rep = 0; rep < 2; ++rep) {
        int j = t + rep * 256;
        float a = b1[j];
        for (int i = 0; i < 256; ++i) a += ln1[i] * W1[i * D_INT + j];
        hdn[j] = fmaxf(a, 0.f);
    }
    __syncthreads();
    float a3 = b2[t];
    for (int i = 0; i < 512; ++i) a3 += hdn[i] * W2[i * D_MAIN + t];
    float x3 = xv + a3;
    float s3 = blockSum256(x3, red);
    float s4 = blockSum256(x3 * x3, red);
    float m2 = s3 * (1.f / 256.f);
    float v2 = s4 * (1.f / 256.f) - m2 * m2;
    float r2 = rsqrtf(v2 + 1e-5f);
    float rv = fmaxf((x3 - m2) * r2 * plns[t] + plnb[t], 0.f);
    __syncthreads();
    ln1[t] = rv;
    __syncthreads();
    if (t < N_CLS) {
        float a = Pb[t];
        for (int i = 0; i < 256; ++i) a += ln1[i] * PW[i * N_CLS + t];
        out[b * N_CLS + t] = a;
    }
}

// ---------- host-side launch ----------
extern "C" void kernel_launch(void* const* d_in, const int* in_sizes, int n_in,
                              void* d_out, int out_size, void* d_ws, size_t ws_size,
                              hipStream_t stream)
{
    (void)in_sizes; (void)n_in; (void)out_size; (void)ws_size;
    const float* x_num   = (const float*)d_in[0];
    const float* cand    = (const float*)d_in[1];
    const int*   cand_y  = (const int*)d_in[2];
    const float* W_lin   = (const float*)d_in[4];
    const float* b_lin   = (const float*)d_in[5];
    const float* W_K     = (const float*)d_in[6];
    const float* b_K     = (const float*)d_in[7];
    const float* Y_emb   = (const float*)d_in[8];
    const float* T_W1    = (const float*)d_in[9];
    const float* T_b1    = (const float*)d_in[10];
    const float* T_W2    = (const float*)d_in[11];
    const float* bp_ln_s = (const float*)d_in[12];
    const float* bp_ln_b = (const float*)d_in[13];
    const float* bp_W1   = (const float*)d_in[14];
    const float* bp_b1   = (const float*)d_in[15];
    const float* bp_W2   = (const float*)d_in[16];
    const float* bp_b2   = (const float*)d_in[17];
    const float* P_ln_s  = (const float*)d_in[18];
    const float* P_ln_b  = (const float*)d_in[19];
    const float* P_W     = (const float*)d_in[20];
    const float* P_b     = (const float*)d_in[21];
    float* outp = (float*)d_out;

    char* ws = (char*)d_ws;
    float* kiall  = (float*)(ws + 0);
    unsigned short* hidden = (unsigned short*)(ws + 0);
    unsigned short* ki_bf = (unsigned short*)(ws + 102400000);
    unsigned short* diffb = (unsigned short*)(ws + 102400000);
    float* mlpbuf = (float*)(ws + 102400000);
    float* scores = (float*)(ws + 153600000);
    u64*   surv   = (u64*)(ws + 153600000);
    const size_t T = 204800000;
    float* xbuf   = (float*)(ws + T + 0);
    float* kbuf   = (float*)(ws + T + 1048576);
    float* x2buf  = (float*)(ws + T + 2097152);
    float* knorm  = (float*)(ws + T + 3145728);
    float* kinorm = (float*)(ws + T + 3149824);
    unsigned short* k_bf = (unsigned short*)(ws + T + 3551232);
    unsigned short* WfH = (unsigned short*)(ws + T + 4206592);  // 256x128 bf16
    unsigned short* WfL = (unsigned short*)(ws + T + 4272128);
    float* bfused = (float*)(ws + T + 4337664);            // 256 f32
    unsigned short* W1t  = (unsigned short*)(ws + T + 4468736);
    unsigned short* W2t  = (unsigned short*)(ws + T + 4730880);
    float* Sbuf   = (float*)(ws + T + 4993024);
    float* wbuf   = (float*)(ws + T + 5386240);
    int*   refI   = (int*)(ws + T + 5779456);
    int*   Ifin   = (int*)(ws + T + 6303744);
    unsigned* tau32 = (unsigned*)(ws + T + 7745536);
    int*   svcnt  = (int*)(ws + T + 7749632);

    // 1. batch encode (exact fp32, fused bf16 emit)
    encode_batch<<<B_ROWS, 256, 0, stream>>>(x_num, W_lin, b_lin, W_K, b_K,
                                             xbuf, kbuf, knorm, k_bf);
    // 2. fused encoder weights -> split/transposed bf16 directly; T-MLP weight transposes
    fuse_weights_split<<<129, 256, 0, stream>>>(W_lin, W_K, b_lin, b_K,
                                                WfH, WfL, bfused);
    cvt_transpose2<<<1024, 256, 0, stream>>>(T_W1, W1t, T_W2, W2t);
    // 3. candidate keys via ONE fused split-bf16 GEMM (fp32-accurate), K=128
    gemm_split3<true><<<dim3(782, 4), 256, 0, stream>>>(
        cand, WfH, WfL, bfused, kiall, ki_bf, N_CAND, D_MAIN, N_FEAT);
    // 4. candidate norms
    rownorms<<<25000, 256, 0, stream>>>(kiall, kinorm, N_CAND);
    // 5. pilot: screen first PCHN candidates, exact top-128 -> surv/svcnt/tau
    screen_gemm<1><<<dim3(8, PCHN / 64), 256, 0, stream>>>(
        k_bf, ki_bf, scores, PCHN, 0, kinorm, nullptr, nullptr, nullptr);
    pilot_select<<<B_ROWS, 256, 0, stream>>>(scores, surv, svcnt, tau32);
    // 6. fused screen+filter over remaining candidates
    screen_gemm<2><<<dim3(8, (N2 + 63) / 64), 256, 0, stream>>>(
        k_bf, ki_bf + (size_t)PCHN * D_MAIN, nullptr, N2, PCHN,
        kinorm + PCHN, tau32, svcnt, surv);
    // 7. final exact top-128 of survivors -> refI
    final_select<<<B_ROWS, 256, 0, stream>>>(surv, svcnt, refI);
    // 8. exact fp32 refine -> top-96 + S
    refine<<<B_ROWS, 256, 0, stream>>>(kbuf, kiall, knorm, kinorm, refI, Ifin, Sbuf);
    // 9. softmax weights
    softmax96<<<B_ROWS, 128, 0, stream>>>(Sbuf, wbuf);
    // 10. gather diff (bf16)
    gather_diff_bf<<<B_ROWS * CTX, 64, 0, stream>>>(kbuf, kiall, Ifin, diffb);
    // 11. T-MLP on MFMA (128x64 tiles, dbuf)
    gemm_bf16<true, true><<<dim3(768, 8), 256, 0, stream>>>(
        diffb, W1t, T_b1, hidden, B_ROWS * CTX, D_INT, D_MAIN);
    gemm_bf16<false, false><<<dim3(768, 4), 256, 0, stream>>>(
        hidden, W2t, nullptr, mlpbuf, B_ROWS * CTX, D_MAIN, D_INT);
    // 12. aggregate
    aggregate<<<B_ROWS, 256, 0, stream>>>(wbuf, Ifin, cand_y, Y_emb, mlpbuf,
                                          xbuf, x2buf);
    // 13. predictor + head
    predictor_head<<<B_ROWS, 256, 0, stream>>>(x2buf, bp_ln_s, bp_ln_b,
                                               bp_W1, bp_b1, bp_W2, bp_b2,
                                               P_ln_s, P_ln_b, P_W, P_b, outp);
}